// Round 1
// baseline (2887.696 us; speedup 1.0000x reference)
//
#include <hip/hip_runtime.h>
#include <hip/hip_bf16.h>
#include <math.h>

#define NTOK 4096
#define DM 1024
#define TSEQ 2048
#define NH 16
#define NKV 4
#define HDIM 64
#define NE 8
#define NFF 2048

__device__ __forceinline__ float silu_f(float v) { return v / (1.0f + expf(-v)); }

// ---------------- RMSNorm: out[row] = x[row] * rsqrt(mean(x^2)+eps) * w ----------------
__global__ __launch_bounds__(256) void rmsnorm_k(const float* __restrict__ x,
                                                 const float* __restrict__ w,
                                                 float* __restrict__ out) {
    int row = blockIdx.x;
    int tid = threadIdx.x;  // 256 threads, 4 floats each
    const float4 v = ((const float4*)(x + (size_t)row * DM))[tid];
    float ss = v.x * v.x + v.y * v.y + v.z * v.z + v.w * v.w;
    for (int off = 32; off; off >>= 1) ss += __shfl_down(ss, off);
    __shared__ float red[4];
    if ((tid & 63) == 0) red[tid >> 6] = ss;
    __syncthreads();
    float tot = red[0] + red[1] + red[2] + red[3];
    float inv = rsqrtf(tot * (1.0f / DM) + 1e-6f);
    const float4 wv = ((const float4*)w)[tid];
    float4 o;
    o.x = v.x * inv * wv.x;
    o.y = v.y * inv * wv.y;
    o.z = v.z * inv * wv.z;
    o.w = v.w * inv * wv.w;
    ((float4*)(out + (size_t)row * DM))[tid] = o;
}

// ---------------- generic fp32 tiled GEMM: C = A(MxK) @ B(KxN) [+epilogue] ----------------
// EPI: 0 = plain, 1 = silu, 2 = add residual R
template <int EPI>
__global__ __launch_bounds__(256) void gemm_k(const float* __restrict__ A,
                                              const float* __restrict__ B,
                                              const float* __restrict__ R,
                                              float* __restrict__ C,
                                              int M, int N, int K) {
    __shared__ float As[16][68];
    __shared__ float Bs[16][68];
    int tid = threadIdx.x;
    int n0 = blockIdx.x * 64, m0 = blockIdx.y * 64;
    int lr = tid >> 2, lk = (tid & 3) << 2;       // A stage: row lr, k-col lk..lk+3
    int bk = tid >> 4, bc = (tid & 15) << 2;      // B stage: k-row bk, col bc..bc+3
    int trow = (tid >> 4) << 2, tcol = (tid & 15) << 2;
    float acc[4][4] = {};
    const float* Ap = A + (size_t)(m0 + lr) * K + lk;
    const float* Bp = B + (size_t)bk * N + n0 + bc;
    for (int k0 = 0; k0 < K; k0 += 16) {
        float4 av = *(const float4*)(Ap + k0);
        float4 bv = *(const float4*)(Bp + (size_t)k0 * N);
        As[lk + 0][lr] = av.x;
        As[lk + 1][lr] = av.y;
        As[lk + 2][lr] = av.z;
        As[lk + 3][lr] = av.w;
        *(float4*)&Bs[bk][bc] = bv;
        __syncthreads();
#pragma unroll
        for (int kk = 0; kk < 16; ++kk) {
            const float4 a = *(const float4*)&As[kk][trow];
            const float4 b = *(const float4*)&Bs[kk][tcol];
            float ar[4] = {a.x, a.y, a.z, a.w};
            float br[4] = {b.x, b.y, b.z, b.w};
#pragma unroll
            for (int i = 0; i < 4; ++i)
#pragma unroll
                for (int j = 0; j < 4; ++j) acc[i][j] = fmaf(ar[i], br[j], acc[i][j]);
        }
        __syncthreads();
    }
#pragma unroll
    for (int i = 0; i < 4; ++i) {
        size_t idx = (size_t)(m0 + trow + i) * N + n0 + tcol;
        float4 o;
        o.x = acc[i][0]; o.y = acc[i][1]; o.z = acc[i][2]; o.w = acc[i][3];
        if (EPI == 1) {
            o.x = silu_f(o.x); o.y = silu_f(o.y); o.z = silu_f(o.z); o.w = silu_f(o.w);
        } else if (EPI == 2) {
            const float4 r4 = *(const float4*)(R + idx);
            o.x += r4.x; o.y += r4.y; o.z += r4.z; o.w += r4.w;
        }
        *(float4*)(C + idx) = o;
    }
}

// ---------------- RoPE in place: buffer layout (NTOK rows, nheads*64 cols) ----------------
__global__ void rope_k(float* __restrict__ x, int nheads) {
    int idx = blockIdx.x * blockDim.x + threadIdx.x;
    int total = NTOK * nheads * 32;
    if (idx >= total) return;
    int j = idx & 31;                       // pair index within head (0..31)
    int hh = (idx >> 5) % nheads;
    int n = idx / (nheads * 32);
    int t = n & (TSEQ - 1);
    float inv = expf(-(float)j * (0.03125f * logf(10000.0f)));
    float s, c;
    sincosf((float)t * inv, &s, &c);
    float* p = x + (size_t)n * (nheads * 64) + hh * 64 + j * 2;
    float x0 = p[0], x1 = p[1];
    p[0] = x0 * c - x1 * s;
    p[1] = x0 * s + x1 * c;
}

// ---------------- causal GQA flash attention, fp32, 32-query tiles ----------------
__global__ __launch_bounds__(256) void attn_k(const float* __restrict__ q,
                                              const float* __restrict__ k,
                                              const float* __restrict__ v,
                                              float* __restrict__ o) {
    __shared__ float Qt[32][68], Kt[32][68], Vt[32][68];
    __shared__ float S[32][33];
    __shared__ float mrow[32], lrow[32], srow[32];
    int tid = threadIdx.x;
    int bh = blockIdx.y;
    int b = bh >> 4, hh = bh & 15;
    int kvh = hh >> 2;
    int q0 = blockIdx.x * 32;
    size_t bT = (size_t)b * TSEQ;
    for (int i = tid; i < 32 * 16; i += 256) {
        int r = i >> 4, c = (i & 15) << 2;
        *(float4*)&Qt[r][c] = *(const float4*)&q[(bT + q0 + r) * DM + hh * HDIM + c];
    }
    if (tid < 32) { mrow[tid] = -INFINITY; lrow[tid] = 0.0f; }
    float oreg[8] = {};
    int r = tid >> 3, dg = (tid & 7) << 3;   // O-update mapping
    int sr = tid >> 3, kb = tid & 7;         // S mapping: cols kb, kb+8, kb+16, kb+24
    int nkt = (q0 >> 5) + 1;
    for (int kt = 0; kt < nkt; ++kt) {
        int k0 = kt << 5;
        __syncthreads();  // protect Kt/Vt/S from previous iteration readers
        for (int i = tid; i < 32 * 16; i += 256) {
            int rr = i >> 4, c = (i & 15) << 2;
            *(float4*)&Kt[rr][c] =
                *(const float4*)&k[(bT + k0 + rr) * (NKV * HDIM) + kvh * HDIM + c];
            *(float4*)&Vt[rr][c] =
                *(const float4*)&v[(bT + k0 + rr) * (NKV * HDIM) + kvh * HDIM + c];
        }
        __syncthreads();
        float s0 = 0, s1 = 0, s2 = 0, s3 = 0;
#pragma unroll
        for (int d = 0; d < 64; d += 4) {
            const float4 qv = *(const float4*)&Qt[sr][d];
            const float4 ka = *(const float4*)&Kt[kb][d];
            const float4 kbv = *(const float4*)&Kt[kb + 8][d];
            const float4 kc = *(const float4*)&Kt[kb + 16][d];
            const float4 kd = *(const float4*)&Kt[kb + 24][d];
            s0 += qv.x * ka.x + qv.y * ka.y + qv.z * ka.z + qv.w * ka.w;
            s1 += qv.x * kbv.x + qv.y * kbv.y + qv.z * kbv.z + qv.w * kbv.w;
            s2 += qv.x * kc.x + qv.y * kc.y + qv.z * kc.z + qv.w * kc.w;
            s3 += qv.x * kd.x + qv.y * kd.y + qv.z * kd.z + qv.w * kd.w;
        }
        int gq = q0 + sr;
        S[sr][kb]      = (k0 + kb      <= gq) ? s0 * 0.125f : -1e30f;
        S[sr][kb + 8]  = (k0 + kb + 8  <= gq) ? s1 * 0.125f : -1e30f;
        S[sr][kb + 16] = (k0 + kb + 16 <= gq) ? s2 * 0.125f : -1e30f;
        S[sr][kb + 24] = (k0 + kb + 24 <= gq) ? s3 * 0.125f : -1e30f;
        __syncthreads();
        if (tid < 32) {
            float mold = mrow[tid];
            float mx = mold;
            for (int kk2 = 0; kk2 < 32; ++kk2) mx = fmaxf(mx, S[tid][kk2]);
            float sc = expf(mold - mx);
            float sum = 0;
            for (int kk2 = 0; kk2 < 32; ++kk2) {
                float p = expf(S[tid][kk2] - mx);
                S[tid][kk2] = p;
                sum += p;
            }
            lrow[tid] = lrow[tid] * sc + sum;
            mrow[tid] = mx;
            srow[tid] = sc;
        }
        __syncthreads();
        float sc = srow[r];
#pragma unroll
        for (int j = 0; j < 8; ++j) oreg[j] *= sc;
        for (int kk2 = 0; kk2 < 32; ++kk2) {
            float p = S[r][kk2];
            const float4 v0 = *(const float4*)&Vt[kk2][dg];
            const float4 v1 = *(const float4*)&Vt[kk2][dg + 4];
            oreg[0] = fmaf(p, v0.x, oreg[0]);
            oreg[1] = fmaf(p, v0.y, oreg[1]);
            oreg[2] = fmaf(p, v0.z, oreg[2]);
            oreg[3] = fmaf(p, v0.w, oreg[3]);
            oreg[4] = fmaf(p, v1.x, oreg[4]);
            oreg[5] = fmaf(p, v1.y, oreg[5]);
            oreg[6] = fmaf(p, v1.w == v1.w ? v1.z : v1.z, oreg[6]);
            oreg[7] = fmaf(p, v1.w, oreg[7]);
        }
    }
    float linv = 1.0f / lrow[r];
    float* op = o + (bT + q0 + r) * DM + hh * HDIM + dg;
#pragma unroll
    for (int j = 0; j < 8; ++j) op[j] = oreg[j] * linv;
}

// ---------------- gate: scores = sigmoid(h2 @ gw) + gb, top-2, counts ----------------
__global__ __launch_bounds__(64) void gate_k(const float* __restrict__ h2,
                                             const float* __restrict__ gw,
                                             const float* __restrict__ gb,
                                             int* __restrict__ top2i,
                                             float* __restrict__ top2w,
                                             int* __restrict__ counts) {
    int n = blockIdx.x;
    int lane = threadIdx.x;
    float acc[8] = {};
    for (int d = lane; d < DM; d += 64) {
        float hv = h2[(size_t)n * DM + d];
        const float4 g0 = ((const float4*)&gw[d * 8])[0];
        const float4 g1 = ((const float4*)&gw[d * 8])[1];
        acc[0] = fmaf(hv, g0.x, acc[0]); acc[1] = fmaf(hv, g0.y, acc[1]);
        acc[2] = fmaf(hv, g0.z, acc[2]); acc[3] = fmaf(hv, g0.w, acc[3]);
        acc[4] = fmaf(hv, g1.x, acc[4]); acc[5] = fmaf(hv, g1.y, acc[5]);
        acc[6] = fmaf(hv, g1.z, acc[6]); acc[7] = fmaf(hv, g1.w, acc[7]);
    }
#pragma unroll
    for (int e = 0; e < 8; ++e)
        for (int off = 32; off; off >>= 1) acc[e] += __shfl_down(acc[e], off);
    if (lane == 0) {
        float s[8];
#pragma unroll
        for (int e = 0; e < 8; ++e) s[e] = 1.0f / (1.0f + expf(-acc[e])) + gb[e];
        int i0 = 0;
#pragma unroll
        for (int e = 1; e < 8; ++e) if (s[e] > s[i0]) i0 = e;
        int i1 = (i0 == 0) ? 1 : 0;
#pragma unroll
        for (int e = 0; e < 8; ++e) if (e != i0 && s[e] > s[i1]) i1 = e;
        float w0 = s[i0], w1 = s[i1];
        float norm = 1.0f / (w0 + w1 + 1e-20f);
        top2i[n * 2] = i0; top2i[n * 2 + 1] = i1;
        top2w[n * 2] = w0 * norm; top2w[n * 2 + 1] = w1 * norm;
        atomicAdd(&counts[i0], 1);
        atomicAdd(&counts[i1], 1);
    }
}

__global__ void zero16_k(int* p) { if (threadIdx.x < 16) p[threadIdx.x] = 0; }

__global__ void scan_k(const int* __restrict__ counts, int* __restrict__ segs) {
    if (threadIdx.x == 0) {
        segs[0] = 0;
        for (int e = 0; e < NE; ++e) segs[e + 1] = segs[e] + counts[e];
    }
}

__global__ void scatter_k(const int* __restrict__ top2i, const float* __restrict__ top2w,
                          const int* __restrict__ segs, int* __restrict__ cursor,
                          int* __restrict__ list, float* __restrict__ wslot,
                          int* __restrict__ slot_of) {
    int idx = blockIdx.x * blockDim.x + threadIdx.x;
    if (idx >= NTOK * 2) return;
    int e = top2i[idx];
    int pos = segs[e] + atomicAdd(&cursor[e], 1);
    list[pos] = idx >> 1;
    wslot[pos] = top2w[idx];
    slot_of[idx] = pos;
}

// ---------------- routed expert w1: hmid = silu(gather(h2) @ w1[e]) ----------------
__global__ __launch_bounds__(256) void moe_w1_k(const float* __restrict__ h2,
                                                const float* __restrict__ w1,
                                                const int* __restrict__ list,
                                                const int* __restrict__ segs,
                                                float* __restrict__ hmid) {
    int e = blockIdx.z;
    int base = segs[e];
    int cnt = segs[e + 1] - base;
    int m0 = blockIdx.y * 64;
    if (m0 >= cnt) return;
    int n0 = blockIdx.x * 64;
    const float* B = w1 + (size_t)e * DM * NFF;
    __shared__ float As[16][68];
    __shared__ float Bs[16][68];
    int tid = threadIdx.x;
    int lr = tid >> 2, lk = (tid & 3) << 2;
    int bk = tid >> 4, bc = (tid & 15) << 2;
    int trow = (tid >> 4) << 2, tcol = (tid & 15) << 2;
    bool aval = (m0 + lr) < cnt;
    const float* Ap = h2 + (size_t)list[base + (aval ? m0 + lr : 0)] * DM + lk;
    float acc[4][4] = {};
    for (int k0 = 0; k0 < DM; k0 += 16) {
        float4 av = aval ? *(const float4*)(Ap + k0) : make_float4(0, 0, 0, 0);
        float4 bv = *(const float4*)(B + (size_t)(k0 + bk) * NFF + n0 + bc);
        As[lk + 0][lr] = av.x; As[lk + 1][lr] = av.y;
        As[lk + 2][lr] = av.z; As[lk + 3][lr] = av.w;
        *(float4*)&Bs[bk][bc] = bv;
        __syncthreads();
#pragma unroll
        for (int kk = 0; kk < 16; ++kk) {
            const float4 a = *(const float4*)&As[kk][trow];
            const float4 b = *(const float4*)&Bs[kk][tcol];
            float ar[4] = {a.x, a.y, a.z, a.w};
            float br[4] = {b.x, b.y, b.z, b.w};
#pragma unroll
            for (int i = 0; i < 4; ++i)
#pragma unroll
                for (int j = 0; j < 4; ++j) acc[i][j] = fmaf(ar[i], br[j], acc[i][j]);
        }
        __syncthreads();
    }
#pragma unroll
    for (int i = 0; i < 4; ++i) {
        int row = m0 + trow + i;
        if (row >= cnt) continue;
        float4 o;
        o.x = silu_f(acc[i][0]); o.y = silu_f(acc[i][1]);
        o.z = silu_f(acc[i][2]); o.w = silu_f(acc[i][3]);
        *(float4*)(hmid + (size_t)(base + row) * NFF + n0 + tcol) = o;
    }
}

// ---------------- routed expert w2: eout = (hmid @ w2[e]) * wslot ----------------
__global__ __launch_bounds__(256) void moe_w2_k(const float* __restrict__ hmid,
                                                const float* __restrict__ w2,
                                                const float* __restrict__ wslot,
                                                const int* __restrict__ segs,
                                                float* __restrict__ eout) {
    int e = blockIdx.z;
    int base = segs[e];
    int cnt = segs[e + 1] - base;
    int m0 = blockIdx.y * 64;
    if (m0 >= cnt) return;
    int n0 = blockIdx.x * 64;
    const float* B = w2 + (size_t)e * NFF * DM;
    __shared__ float As[16][68];
    __shared__ float Bs[16][68];
    int tid = threadIdx.x;
    int lr = tid >> 2, lk = (tid & 3) << 2;
    int bk = tid >> 4, bc = (tid & 15) << 2;
    int trow = (tid >> 4) << 2, tcol = (tid & 15) << 2;
    bool aval = (m0 + lr) < cnt;
    const float* Ap = hmid + (size_t)(base + (aval ? m0 + lr : 0)) * NFF + lk;
    float acc[4][4] = {};
    for (int k0 = 0; k0 < NFF; k0 += 16) {
        float4 av = aval ? *(const float4*)(Ap + k0) : make_float4(0, 0, 0, 0);
        float4 bv = *(const float4*)(B + (size_t)(k0 + bk) * DM + n0 + bc);
        As[lk + 0][lr] = av.x; As[lk + 1][lr] = av.y;
        As[lk + 2][lr] = av.z; As[lk + 3][lr] = av.w;
        *(float4*)&Bs[bk][bc] = bv;
        __syncthreads();
#pragma unroll
        for (int kk = 0; kk < 16; ++kk) {
            const float4 a = *(const float4*)&As[kk][trow];
            const float4 b = *(const float4*)&Bs[kk][tcol];
            float ar[4] = {a.x, a.y, a.z, a.w};
            float br[4] = {b.x, b.y, b.z, b.w};
#pragma unroll
            for (int i = 0; i < 4; ++i)
#pragma unroll
                for (int j = 0; j < 4; ++j) acc[i][j] = fmaf(ar[i], br[j], acc[i][j]);
        }
        __syncthreads();
    }
#pragma unroll
    for (int i = 0; i < 4; ++i) {
        int row = m0 + trow + i;
        if (row >= cnt) continue;
        float wgt = wslot[base + row];
        float4 o;
        o.x = acc[i][0] * wgt; o.y = acc[i][1] * wgt;
        o.z = acc[i][2] * wgt; o.w = acc[i][3] * wgt;
        *(float4*)(eout + (size_t)(base + row) * DM + n0 + tcol) = o;
    }
}

// ---------------- combine: out[n] += eout[slot0(n)] + eout[slot1(n)] ----------------
__global__ __launch_bounds__(256) void combine_k(const float* __restrict__ eout,
                                                 const int* __restrict__ slot_of,
                                                 float* __restrict__ out) {
    int idx = blockIdx.x * blockDim.x + threadIdx.x;  // over NTOK * DM/4
    int n = idx >> 8;         // DM/4 = 256 float4 per row
    int c = idx & 255;
    const float4 a = ((const float4*)(eout + (size_t)slot_of[n * 2] * DM))[c];
    const float4 b = ((const float4*)(eout + (size_t)slot_of[n * 2 + 1] * DM))[c];
    float4 o = ((float4*)out)[idx];
    o.x += a.x + b.x; o.y += a.y + b.y; o.z += a.z + b.z; o.w += a.w + b.w;
    ((float4*)out)[idx] = o;
}

extern "C" void kernel_launch(void* const* d_in, const int* in_sizes, int n_in,
                              void* d_out, int out_size, void* d_ws, size_t ws_size,
                              hipStream_t stream) {
    (void)in_sizes; (void)n_in; (void)out_size; (void)ws_size;
    const float* x   = (const float*)d_in[0];
    const float* anw = (const float*)d_in[1];
    const float* wq  = (const float*)d_in[2];
    const float* wk  = (const float*)d_in[3];
    const float* wv  = (const float*)d_in[4];
    const float* wo  = (const float*)d_in[5];
    const float* fnw = (const float*)d_in[6];
    const float* gw  = (const float*)d_in[7];
    const float* gb  = (const float*)d_in[8];
    const float* ew1 = (const float*)d_in[9];
    const float* ew2 = (const float*)d_in[10];
    const float* sw1 = (const float*)d_in[11];
    const float* sw2 = (const float*)d_in[12];
    float* out = (float*)d_out;

    float* ws = (float*)d_ws;
    float* bufA = ws;                   // 4M floats: h -> attn_out -> h2
    float* bufB = bufA + 4194304;       // 4M floats: q -> x1
    float* kbuf = bufB + 4194304;       // 1M floats
    float* vbuf = kbuf + 1048576;       // 1M floats
    float* bufE = vbuf + 1048576;       // 8M floats: shared_mid -> eout
    float* bufF = bufE + 8388608;       // 16M floats: hmid
    float* fmeta = bufF + 16777216;
    int*   top2i = (int*)fmeta;                  // 8192 ints
    float* top2w = fmeta + 8192;                 // 8192 floats
    int*   meta  = (int*)(fmeta + 16384);        // counts[8], cursor[8], segs[9]
    int*   counts = meta;
    int*   cursor = meta + 8;
    int*   segs   = meta + 16;
    int*   list   = meta + 32;                   // 8192 ints
    float* wslot  = (float*)(meta + 32 + 8192);  // 8192 floats
    int*   slot_of = (int*)(wslot + 8192);       // 8192 ints

    // 1. h = rmsnorm(x, attn_norm_w)
    rmsnorm_k<<<NTOK, 256, 0, stream>>>(x, anw, bufA);
    // 2. q/k/v projections
    gemm_k<0><<<dim3(16, 64), 256, 0, stream>>>(bufA, wq, nullptr, bufB, NTOK, 1024, 1024);
    gemm_k<0><<<dim3(4, 64), 256, 0, stream>>>(bufA, wk, nullptr, kbuf, NTOK, 256, 1024);
    gemm_k<0><<<dim3(4, 64), 256, 0, stream>>>(bufA, wv, nullptr, vbuf, NTOK, 256, 1024);
    // 3. RoPE in place
    rope_k<<<(NTOK * NH * 32 + 255) / 256, 256, 0, stream>>>(bufB, NH);
    rope_k<<<(NTOK * NKV * 32 + 255) / 256, 256, 0, stream>>>(kbuf, NKV);
    // 4. attention -> bufA
    attn_k<<<dim3(TSEQ / 32, 32), 256, 0, stream>>>(bufB, kbuf, vbuf, bufA);
    // 5. x1 = attn_out @ wo + x -> bufB
    gemm_k<2><<<dim3(16, 64), 256, 0, stream>>>(bufA, wo, x, bufB, NTOK, 1024, 1024);
    // 6. h2 = rmsnorm(x1, ffn_norm_w) -> bufA
    rmsnorm_k<<<NTOK, 256, 0, stream>>>(bufB, fnw, bufA);
    // 7. gate + routing
    zero16_k<<<1, 64, 0, stream>>>(meta);
    gate_k<<<NTOK, 64, 0, stream>>>(bufA, gw, gb, top2i, top2w, counts);
    scan_k<<<1, 1, 0, stream>>>(counts, segs);
    scatter_k<<<32, 256, 0, stream>>>(top2i, top2w, segs, cursor, list, wslot, slot_of);
    // 8. shared expert: mid = silu(h2 @ sw1); out = mid @ sw2 + x1
    gemm_k<1><<<dim3(32, 64), 256, 0, stream>>>(bufA, sw1, nullptr, bufE, NTOK, NFF, 1024);
    gemm_k<2><<<dim3(16, 64), 256, 0, stream>>>(bufE, sw2, bufB, out, NTOK, 1024, NFF);
    // 9. routed experts
    moe_w1_k<<<dim3(32, 64, NE), 256, 0, stream>>>(bufA, ew1, list, segs, bufF);
    moe_w2_k<<<dim3(16, 64, NE), 256, 0, stream>>>(bufF, ew2, wslot, segs, bufE);
    combine_k<<<NTOK, 256, 0, stream>>>(bufE, slot_of, out);
}

// Round 2
// 1722.882 us; speedup vs baseline: 1.6761x; 1.6761x over previous
//
#include <hip/hip_runtime.h>
#include <math.h>

#define NTOK 4096
#define DM 1024
#define TSEQ 2048
#define NH 16
#define NKV 4
#define HDIM 64
#define NE 8
#define NFF 2048

typedef float f4v __attribute__((ext_vector_type(4)));
typedef short b8v __attribute__((ext_vector_type(8)));
typedef unsigned short u16;

__device__ __forceinline__ float silu_f(float v) { return v / (1.0f + expf(-v)); }

__device__ __forceinline__ u16 f2b(float f) {
    union { float f; unsigned u; } x{f};
    unsigned r = (x.u + 0x7FFFu + ((x.u >> 16) & 1u)) >> 16;
    return (u16)r;
}

// ---------------- RMSNorm ----------------
__global__ __launch_bounds__(256) void rmsnorm_k(const float* __restrict__ x,
                                                 const float* __restrict__ w,
                                                 float* __restrict__ out) {
    int row = blockIdx.x;
    int tid = threadIdx.x;
    const float4 v = ((const float4*)(x + (size_t)row * DM))[tid];
    float ss = v.x * v.x + v.y * v.y + v.z * v.z + v.w * v.w;
    for (int off = 32; off; off >>= 1) ss += __shfl_down(ss, off);
    __shared__ float red[4];
    if ((tid & 63) == 0) red[tid >> 6] = ss;
    __syncthreads();
    float tot = red[0] + red[1] + red[2] + red[3];
    float inv = rsqrtf(tot * (1.0f / DM) + 1e-6f);
    const float4 wv = ((const float4*)w)[tid];
    float4 o;
    o.x = v.x * inv * wv.x;
    o.y = v.y * inv * wv.y;
    o.z = v.z * inv * wv.z;
    o.w = v.w * inv * wv.w;
    ((float4*)(out + (size_t)row * DM))[tid] = o;
}

// ---------------- fp32 tiled GEMM (QKV / Wo path — kept fp32 for gate fidelity) ----------------
template <int EPI>  // 0 plain, 2 add residual R
__global__ __launch_bounds__(256) void gemm_k(const float* __restrict__ A,
                                              const float* __restrict__ B,
                                              const float* __restrict__ R,
                                              float* __restrict__ C,
                                              int M, int N, int K) {
    __shared__ float As[16][68];
    __shared__ float Bs[16][68];
    int tid = threadIdx.x;
    int n0 = blockIdx.x * 64, m0 = blockIdx.y * 64;
    int lr = tid >> 2, lk = (tid & 3) << 2;
    int bk = tid >> 4, bc = (tid & 15) << 2;
    int trow = (tid >> 4) << 2, tcol = (tid & 15) << 2;
    float acc[4][4] = {};
    const float* Ap = A + (size_t)(m0 + lr) * K + lk;
    const float* Bp = B + (size_t)bk * N + n0 + bc;
    for (int k0 = 0; k0 < K; k0 += 16) {
        float4 av = *(const float4*)(Ap + k0);
        float4 bv = *(const float4*)(Bp + (size_t)k0 * N);
        As[lk + 0][lr] = av.x;
        As[lk + 1][lr] = av.y;
        As[lk + 2][lr] = av.z;
        As[lk + 3][lr] = av.w;
        *(float4*)&Bs[bk][bc] = bv;
        __syncthreads();
#pragma unroll
        for (int kk = 0; kk < 16; ++kk) {
            const float4 a = *(const float4*)&As[kk][trow];
            const float4 b = *(const float4*)&Bs[kk][tcol];
            float ar[4] = {a.x, a.y, a.z, a.w};
            float br[4] = {b.x, b.y, b.z, b.w};
#pragma unroll
            for (int i = 0; i < 4; ++i)
#pragma unroll
                for (int j = 0; j < 4; ++j) acc[i][j] = fmaf(ar[i], br[j], acc[i][j]);
        }
        __syncthreads();
    }
#pragma unroll
    for (int i = 0; i < 4; ++i) {
        size_t idx = (size_t)(m0 + trow + i) * N + n0 + tcol;
        float4 o;
        o.x = acc[i][0]; o.y = acc[i][1]; o.z = acc[i][2]; o.w = acc[i][3];
        if (EPI == 2) {
            const float4 r4 = *(const float4*)(R + idx);
            o.x += r4.x; o.y += r4.y; o.z += r4.z; o.w += r4.w;
        }
        *(float4*)(C + idx) = o;
    }
}

// ---------------- RoPE in place ----------------
__global__ void rope_k(float* __restrict__ x, int nheads) {
    int idx = blockIdx.x * blockDim.x + threadIdx.x;
    int total = NTOK * nheads * 32;
    if (idx >= total) return;
    int j = idx & 31;
    int hh = (idx >> 5) % nheads;
    int n = idx / (nheads * 32);
    int t = n & (TSEQ - 1);
    float inv = expf(-(float)j * (0.03125f * logf(10000.0f)));
    float s, c;
    sincosf((float)t * inv, &s, &c);
    float* p = x + (size_t)n * (nheads * 64) + hh * 64 + j * 2;
    float x0 = p[0], x1 = p[1];
    p[0] = x0 * c - x1 * s;
    p[1] = x0 * s + x1 * c;
}

// ---------------- causal GQA flash attention, fp32 (unchanged, verified) ----------------
__global__ __launch_bounds__(256) void attn_k(const float* __restrict__ q,
                                              const float* __restrict__ k,
                                              const float* __restrict__ v,
                                              float* __restrict__ o) {
    __shared__ float Qt[32][68], Kt[32][68], Vt[32][68];
    __shared__ float S[32][33];
    __shared__ float mrow[32], lrow[32], srow[32];
    int tid = threadIdx.x;
    int bh = blockIdx.y;
    int b = bh >> 4, hh = bh & 15;
    int kvh = hh >> 2;
    int q0 = blockIdx.x * 32;
    size_t bT = (size_t)b * TSEQ;
    for (int i = tid; i < 32 * 16; i += 256) {
        int r = i >> 4, c = (i & 15) << 2;
        *(float4*)&Qt[r][c] = *(const float4*)&q[(bT + q0 + r) * DM + hh * HDIM + c];
    }
    if (tid < 32) { mrow[tid] = -INFINITY; lrow[tid] = 0.0f; }
    float oreg[8] = {};
    int r = tid >> 3, dg = (tid & 7) << 3;
    int sr = tid >> 3, kb = tid & 7;
    int nkt = (q0 >> 5) + 1;
    for (int kt = 0; kt < nkt; ++kt) {
        int k0 = kt << 5;
        __syncthreads();
        for (int i = tid; i < 32 * 16; i += 256) {
            int rr = i >> 4, c = (i & 15) << 2;
            *(float4*)&Kt[rr][c] =
                *(const float4*)&k[(bT + k0 + rr) * (NKV * HDIM) + kvh * HDIM + c];
            *(float4*)&Vt[rr][c] =
                *(const float4*)&v[(bT + k0 + rr) * (NKV * HDIM) + kvh * HDIM + c];
        }
        __syncthreads();
        float s0 = 0, s1 = 0, s2 = 0, s3 = 0;
#pragma unroll
        for (int d = 0; d < 64; d += 4) {
            const float4 qv = *(const float4*)&Qt[sr][d];
            const float4 ka = *(const float4*)&Kt[kb][d];
            const float4 kbv = *(const float4*)&Kt[kb + 8][d];
            const float4 kc = *(const float4*)&Kt[kb + 16][d];
            const float4 kd = *(const float4*)&Kt[kb + 24][d];
            s0 += qv.x * ka.x + qv.y * ka.y + qv.z * ka.z + qv.w * ka.w;
            s1 += qv.x * kbv.x + qv.y * kbv.y + qv.z * kbv.z + qv.w * kbv.w;
            s2 += qv.x * kc.x + qv.y * kc.y + qv.z * kc.z + qv.w * kc.w;
            s3 += qv.x * kd.x + qv.y * kd.y + qv.z * kd.z + qv.w * kd.w;
        }
        int gq = q0 + sr;
        S[sr][kb]      = (k0 + kb      <= gq) ? s0 * 0.125f : -1e30f;
        S[sr][kb + 8]  = (k0 + kb + 8  <= gq) ? s1 * 0.125f : -1e30f;
        S[sr][kb + 16] = (k0 + kb + 16 <= gq) ? s2 * 0.125f : -1e30f;
        S[sr][kb + 24] = (k0 + kb + 24 <= gq) ? s3 * 0.125f : -1e30f;
        __syncthreads();
        if (tid < 32) {
            float mold = mrow[tid];
            float mx = mold;
            for (int kk2 = 0; kk2 < 32; ++kk2) mx = fmaxf(mx, S[tid][kk2]);
            float sc = expf(mold - mx);
            float sum = 0;
            for (int kk2 = 0; kk2 < 32; ++kk2) {
                float p = expf(S[tid][kk2] - mx);
                S[tid][kk2] = p;
                sum += p;
            }
            lrow[tid] = lrow[tid] * sc + sum;
            mrow[tid] = mx;
            srow[tid] = sc;
        }
        __syncthreads();
        float sc = srow[r];
#pragma unroll
        for (int j = 0; j < 8; ++j) oreg[j] *= sc;
        for (int kk2 = 0; kk2 < 32; ++kk2) {
            float p = S[r][kk2];
            const float4 v0 = *(const float4*)&Vt[kk2][dg];
            const float4 v1 = *(const float4*)&Vt[kk2][dg + 4];
            oreg[0] = fmaf(p, v0.x, oreg[0]);
            oreg[1] = fmaf(p, v0.y, oreg[1]);
            oreg[2] = fmaf(p, v0.z, oreg[2]);
            oreg[3] = fmaf(p, v0.w, oreg[3]);
            oreg[4] = fmaf(p, v1.x, oreg[4]);
            oreg[5] = fmaf(p, v1.y, oreg[5]);
            oreg[6] = fmaf(p, v1.z, oreg[6]);
            oreg[7] = fmaf(p, v1.w, oreg[7]);
        }
    }
    float linv = 1.0f / lrow[r];
    float* op = o + (bT + q0 + r) * DM + hh * HDIM + dg;
#pragma unroll
    for (int j = 0; j < 8; ++j) op[j] = oreg[j] * linv;
}

// ---------------- gate (fp32, unchanged) ----------------
__global__ __launch_bounds__(64) void gate_k(const float* __restrict__ h2,
                                             const float* __restrict__ gw,
                                             const float* __restrict__ gb,
                                             int* __restrict__ top2i,
                                             float* __restrict__ top2w,
                                             int* __restrict__ counts) {
    int n = blockIdx.x;
    int lane = threadIdx.x;
    float acc[8] = {};
    for (int d = lane; d < DM; d += 64) {
        float hv = h2[(size_t)n * DM + d];
        const float4 g0 = ((const float4*)&gw[d * 8])[0];
        const float4 g1 = ((const float4*)&gw[d * 8])[1];
        acc[0] = fmaf(hv, g0.x, acc[0]); acc[1] = fmaf(hv, g0.y, acc[1]);
        acc[2] = fmaf(hv, g0.z, acc[2]); acc[3] = fmaf(hv, g0.w, acc[3]);
        acc[4] = fmaf(hv, g1.x, acc[4]); acc[5] = fmaf(hv, g1.y, acc[5]);
        acc[6] = fmaf(hv, g1.z, acc[6]); acc[7] = fmaf(hv, g1.w, acc[7]);
    }
#pragma unroll
    for (int e = 0; e < 8; ++e)
        for (int off = 32; off; off >>= 1) acc[e] += __shfl_down(acc[e], off);
    if (lane == 0) {
        float s[8];
#pragma unroll
        for (int e = 0; e < 8; ++e) s[e] = 1.0f / (1.0f + expf(-acc[e])) + gb[e];
        int i0 = 0;
#pragma unroll
        for (int e = 1; e < 8; ++e) if (s[e] > s[i0]) i0 = e;
        int i1 = (i0 == 0) ? 1 : 0;
#pragma unroll
        for (int e = 0; e < 8; ++e) if (e != i0 && s[e] > s[i1]) i1 = e;
        float w0 = s[i0], w1 = s[i1];
        float norm = 1.0f / (w0 + w1 + 1e-20f);
        top2i[n * 2] = i0; top2i[n * 2 + 1] = i1;
        top2w[n * 2] = w0 * norm; top2w[n * 2 + 1] = w1 * norm;
        atomicAdd(&counts[i0], 1);
        atomicAdd(&counts[i1], 1);
    }
}

__global__ void zero16_k(int* p) { if (threadIdx.x < 16) p[threadIdx.x] = 0; }

__global__ void scan_k(const int* __restrict__ counts, int* __restrict__ segs) {
    if (threadIdx.x == 0) {
        segs[0] = 0;
        for (int e = 0; e < NE; ++e) segs[e + 1] = segs[e] + counts[e];
    }
}

__global__ void scatter_k(const int* __restrict__ top2i, const float* __restrict__ top2w,
                          const int* __restrict__ segs, int* __restrict__ cursor,
                          int* __restrict__ list, float* __restrict__ wslot,
                          int* __restrict__ slot_of) {
    int idx = blockIdx.x * blockDim.x + threadIdx.x;
    if (idx >= NTOK * 2) return;
    int e = top2i[idx];
    int pos = segs[e] + atomicAdd(&cursor[e], 1);
    list[pos] = idx >> 1;
    wslot[pos] = top2w[idx];
    slot_of[idx] = pos;
}

// ---------------- fp32 -> bf16 cast (contiguous) ----------------
__global__ __launch_bounds__(256) void castbf_k(const float* __restrict__ in,
                                                u16* __restrict__ out) {
    int idx = blockIdx.x * 256 + threadIdx.x;
    const float4 a = ((const float4*)in)[idx * 2];
    const float4 b = ((const float4*)in)[idx * 2 + 1];
    ushort4 o0, o1;
    o0.x = f2b(a.x); o0.y = f2b(a.y); o0.z = f2b(a.z); o0.w = f2b(a.w);
    o1.x = f2b(b.x); o1.y = f2b(b.y); o1.z = f2b(b.z); o1.w = f2b(b.w);
    ((ushort4*)out)[idx * 2] = o0;
    ((ushort4*)out)[idx * 2 + 1] = o1;
}

// ---------------- transpose + cast: in (R x C fp32) -> out (C x R bf16), batched over z ----------------
__global__ __launch_bounds__(256) void tcast_k(const float* __restrict__ in,
                                               u16* __restrict__ out, int R, int C) {
    size_t boff = (size_t)blockIdx.z * R * C;
    in += boff; out += boff;
    __shared__ float tl[32][33];
    int r0 = blockIdx.y << 5, c0 = blockIdx.x << 5;
    int lr = threadIdx.x >> 3, lc = (threadIdx.x & 7) << 2;
    const float4 v = *(const float4*)&in[(size_t)(r0 + lr) * C + c0 + lc];
    tl[lr][lc] = v.x; tl[lr][lc + 1] = v.y; tl[lr][lc + 2] = v.z; tl[lr][lc + 3] = v.w;
    __syncthreads();
    ushort4 o;
    o.x = f2b(tl[lc + 0][lr]); o.y = f2b(tl[lc + 1][lr]);
    o.z = f2b(tl[lc + 2][lr]); o.w = f2b(tl[lc + 3][lr]);
    *(ushort4*)&out[(size_t)(c0 + lr) * R + r0 + lc] = o;
}

// ---------------- bf16 MFMA GEMM: C = A(MxK) @ Bt(NxK)^T, 128x128 tile, 4 waves ----------------
// EPI: 0 plain f32, 1 silu->bf16, 2 +R ->f32, 3 *wslot ->f32
template <int EPI, int MOE, int GATHER>
__global__ __launch_bounds__(256) void mgemm_k(const u16* __restrict__ A,
                                               const u16* __restrict__ Bt,
                                               const float* __restrict__ R,
                                               const float* __restrict__ wslot,
                                               const int* __restrict__ list,
                                               const int* __restrict__ segs,
                                               float* __restrict__ Cf,
                                               u16* __restrict__ Cb,
                                               int M, int N, int K) {
    __shared__ u16 As[128 * 40];  // +8 pad per row: ds_read_b128 ~2-way bank aliasing
    __shared__ u16 Bs[128 * 40];
    int e = MOE ? blockIdx.z : 0;
    int base = 0, cnt = M;
    if (MOE) { base = segs[e]; cnt = segs[e + 1] - base; }
    int m0 = blockIdx.y * 128;
    if (m0 >= cnt) return;
    int n0 = blockIdx.x * 128;
    const u16* Bte = Bt + (size_t)e * N * K;
    int t = threadIdx.x;
    int l = t & 63, w = t >> 6;
    int wr = w >> 1, wc = w & 1;
    int srow = t >> 2, scol = (t & 3) << 3;
    const u16* ag[2];
    const u16* bg[2];
#pragma unroll
    for (int i = 0; i < 2; ++i) {
        int r = m0 + i * 64 + srow;
        int ar;
        if (MOE) {
            int rc = r < cnt ? r : cnt - 1;
            ar = GATHER ? list[base + rc] : base + rc;
        } else {
            ar = r;
        }
        ag[i] = A + (size_t)ar * K + scol;
        bg[i] = Bte + (size_t)(n0 + i * 64 + srow) * K + scol;
    }
    f4v acc[4][4];
#pragma unroll
    for (int m = 0; m < 4; ++m)
#pragma unroll
        for (int n = 0; n < 4; ++n) acc[m][n] = (f4v)0.0f;
    int kh = (l >> 4) << 3;
    for (int k0 = 0; k0 < K; k0 += 32) {
        b8v va0 = *(const b8v*)(ag[0] + k0);
        b8v va1 = *(const b8v*)(ag[1] + k0);
        b8v vb0 = *(const b8v*)(bg[0] + k0);
        b8v vb1 = *(const b8v*)(bg[1] + k0);
        __syncthreads();
        *(b8v*)&As[srow * 40 + scol] = va0;
        *(b8v*)&As[(64 + srow) * 40 + scol] = va1;
        *(b8v*)&Bs[srow * 40 + scol] = vb0;
        *(b8v*)&Bs[(64 + srow) * 40 + scol] = vb1;
        __syncthreads();
        b8v af[4], bf[4];
#pragma unroll
        for (int m = 0; m < 4; ++m)
            af[m] = *(const b8v*)&As[(wr * 64 + m * 16 + (l & 15)) * 40 + kh];
#pragma unroll
        for (int n = 0; n < 4; ++n)
            bf[n] = *(const b8v*)&Bs[(wc * 64 + n * 16 + (l & 15)) * 40 + kh];
#pragma unroll
        for (int m = 0; m < 4; ++m)
#pragma unroll
            for (int n = 0; n < 4; ++n)
                acc[m][n] = __builtin_amdgcn_mfma_f32_16x16x32_bf16(af[m], bf[n], acc[m][n], 0, 0, 0);
    }
#pragma unroll
    for (int m = 0; m < 4; ++m) {
        int r0l = m0 + wr * 64 + m * 16 + ((l >> 4) << 2);
#pragma unroll
        for (int n = 0; n < 4; ++n) {
            int col = n0 + wc * 64 + n * 16 + (l & 15);
            f4v c = acc[m][n];
#pragma unroll
            for (int j = 0; j < 4; ++j) {
                int row = r0l + j;
                if (MOE && row >= cnt) continue;
                float v = c[j];
                if (EPI == 1) {
                    v = silu_f(v);
                    Cb[(size_t)(base + row) * N + col] = f2b(v);
                } else if (EPI == 2) {
                    size_t idx = (size_t)row * N + col;
                    Cf[idx] = v + R[idx];
                } else if (EPI == 3) {
                    Cf[(size_t)(base + row) * N + col] = v * wslot[base + row];
                } else {
                    Cf[(size_t)row * N + col] = v;
                }
            }
        }
    }
}

// ---------------- combine ----------------
__global__ __launch_bounds__(256) void combine_k(const float* __restrict__ eout,
                                                 const int* __restrict__ slot_of,
                                                 float* __restrict__ out) {
    int idx = blockIdx.x * blockDim.x + threadIdx.x;
    int n = idx >> 8;
    int c = idx & 255;
    const float4 a = ((const float4*)(eout + (size_t)slot_of[n * 2] * DM))[c];
    const float4 b = ((const float4*)(eout + (size_t)slot_of[n * 2 + 1] * DM))[c];
    float4 o = ((float4*)out)[idx];
    o.x += a.x + b.x; o.y += a.y + b.y; o.z += a.z + b.z; o.w += a.w + b.w;
    ((float4*)out)[idx] = o;
}

extern "C" void kernel_launch(void* const* d_in, const int* in_sizes, int n_in,
                              void* d_out, int out_size, void* d_ws, size_t ws_size,
                              hipStream_t stream) {
    (void)in_sizes; (void)n_in; (void)out_size; (void)ws_size;
    const float* x   = (const float*)d_in[0];
    const float* anw = (const float*)d_in[1];
    const float* wq  = (const float*)d_in[2];
    const float* wk  = (const float*)d_in[3];
    const float* wv  = (const float*)d_in[4];
    const float* wo  = (const float*)d_in[5];
    const float* fnw = (const float*)d_in[6];
    const float* gw  = (const float*)d_in[7];
    const float* gb  = (const float*)d_in[8];
    const float* ew1 = (const float*)d_in[9];
    const float* ew2 = (const float*)d_in[10];
    const float* sw1 = (const float*)d_in[11];
    const float* sw2 = (const float*)d_in[12];
    float* out = (float*)d_out;

    float* ws = (float*)d_ws;
    const size_t M1 = 1024 * 1024;
    float* bufA  = ws;              // 4M fl: h -> attn_out -> h2(f32)
    float* bufB  = bufA + 4 * M1;   // 4M fl: q -> x1
    float* kbuf  = bufB + 4 * M1;   // 1M fl
    float* vbuf  = kbuf + 1 * M1;   // 1M fl
    u16*   h2b   = (u16*)(vbuf + 1 * M1);       // 4M bf16 (2M fl)
    u16*   midb  = (u16*)(ws + 12 * M1);        // 8M bf16 (4M fl)
    u16*   hmidb = (u16*)(ws + 16 * M1);        // 16M bf16 (8M fl)
    float* eoutb = ws + 24 * M1;                // 8M fl
    u16*   sw1t  = (u16*)(ws + 32 * M1);        // 2M bf16
    u16*   sw2t  = (u16*)(ws + 33 * M1);        // 2M bf16
    u16*   ew1t  = (u16*)(ws + 34 * M1);        // 16M bf16
    u16*   ew2t  = (u16*)(ws + 42 * M1);        // 16M bf16
    float* fmeta = ws + 50 * M1;
    int*   top2i = (int*)fmeta;
    float* top2w = fmeta + 8192;
    int*   meta   = (int*)(fmeta + 16384);
    int*   counts = meta;
    int*   cursor = meta + 8;
    int*   segs   = meta + 16;
    int*   list   = meta + 32;
    float* wslot  = (float*)(meta + 32 + 8192);
    int*   slot_of = (int*)(wslot + 8192);

    // weight transpose+cast to bf16 N x K (B^T layout for MFMA)
    tcast_k<<<dim3(NFF / 32, DM / 32, 1), 256, 0, stream>>>(sw1, sw1t, DM, NFF);
    tcast_k<<<dim3(DM / 32, NFF / 32, 1), 256, 0, stream>>>(sw2, sw2t, NFF, DM);
    tcast_k<<<dim3(NFF / 32, DM / 32, NE), 256, 0, stream>>>(ew1, ew1t, DM, NFF);
    tcast_k<<<dim3(DM / 32, NFF / 32, NE), 256, 0, stream>>>(ew2, ew2t, NFF, DM);

    // 1. h = rmsnorm(x)
    rmsnorm_k<<<NTOK, 256, 0, stream>>>(x, anw, bufA);
    // 2. q/k/v projections (fp32)
    gemm_k<0><<<dim3(16, 64), 256, 0, stream>>>(bufA, wq, nullptr, bufB, NTOK, 1024, 1024);
    gemm_k<0><<<dim3(4, 64), 256, 0, stream>>>(bufA, wk, nullptr, kbuf, NTOK, 256, 1024);
    gemm_k<0><<<dim3(4, 64), 256, 0, stream>>>(bufA, wv, nullptr, vbuf, NTOK, 256, 1024);
    // 3. RoPE
    rope_k<<<(NTOK * NH * 32 + 255) / 256, 256, 0, stream>>>(bufB, NH);
    rope_k<<<(NTOK * NKV * 32 + 255) / 256, 256, 0, stream>>>(kbuf, NKV);
    // 4. attention -> bufA
    attn_k<<<dim3(TSEQ / 32, 32), 256, 0, stream>>>(bufB, kbuf, vbuf, bufA);
    // 5. x1 = attn_out @ wo + x -> bufB
    gemm_k<2><<<dim3(16, 64), 256, 0, stream>>>(bufA, wo, x, bufB, NTOK, 1024, 1024);
    // 6. h2 = rmsnorm(x1) -> bufA (fp32, feeds gate); bf16 copy -> h2b
    rmsnorm_k<<<NTOK, 256, 0, stream>>>(bufB, fnw, bufA);
    castbf_k<<<2048, 256, 0, stream>>>(bufA, h2b);
    // 7. gate + routing (fp32)
    zero16_k<<<1, 64, 0, stream>>>(meta);
    gate_k<<<NTOK, 64, 0, stream>>>(bufA, gw, gb, top2i, top2w, counts);
    scan_k<<<1, 1, 0, stream>>>(counts, segs);
    scatter_k<<<32, 256, 0, stream>>>(top2i, top2w, segs, cursor, list, wslot, slot_of);
    // 8. shared expert (bf16 MFMA): mid = silu(h2 @ sw1); out = mid @ sw2 + x1
    mgemm_k<1, 0, 0><<<dim3(NFF / 128, NTOK / 128, 1), 256, 0, stream>>>(
        h2b, sw1t, nullptr, nullptr, nullptr, nullptr, nullptr, midb, NTOK, NFF, DM);
    mgemm_k<2, 0, 0><<<dim3(DM / 128, NTOK / 128, 1), 256, 0, stream>>>(
        midb, sw2t, bufB, nullptr, nullptr, nullptr, out, nullptr, NTOK, DM, NFF);
    // 9. routed experts (bf16 MFMA)
    mgemm_k<1, 1, 1><<<dim3(NFF / 128, NTOK / 128, NE), 256, 0, stream>>>(
        h2b, ew1t, nullptr, nullptr, list, segs, nullptr, hmidb, NTOK, NFF, DM);
    mgemm_k<3, 1, 0><<<dim3(DM / 128, NTOK / 128, NE), 256, 0, stream>>>(
        hmidb, ew2t, nullptr, wslot, nullptr, segs, eoutb, nullptr, 2 * NTOK, DM, NFF);
    combine_k<<<NTOK, 256, 0, stream>>>(eoutb, slot_of, out);
}

// Round 3
// 1244.355 us; speedup vs baseline: 2.3206x; 1.3846x over previous
//
#include <hip/hip_runtime.h>
#include <math.h>

#define NTOK 4096
#define DM 1024
#define TSEQ 2048
#define NH 16
#define NKV 4
#define HDIM 64
#define NE 8
#define NFF 2048
#define QKVN 1536

typedef float f4v __attribute__((ext_vector_type(4)));
typedef short b8v __attribute__((ext_vector_type(8)));
typedef unsigned short u16;

__device__ __forceinline__ float silu_f(float v) { return v / (1.0f + expf(-v)); }

__device__ __forceinline__ u16 f2b(float f) {
    union { float f; unsigned u; } x{f};
    unsigned r = (x.u + 0x7FFFu + ((x.u >> 16) & 1u)) >> 16;
    return (u16)r;
}
__device__ __forceinline__ float b2f(u16 b) {
    union { unsigned u; float f; } x;
    x.u = ((unsigned)b) << 16;
    return x.f;
}

// ---------------- RMSNorm, MODE 0: write hi/lo bf16 split; MODE 1: write f32 + plain bf16 ----
template <int MODE>
__global__ __launch_bounds__(256) void rmsnorm2_k(const float* __restrict__ x,
                                                  const float* __restrict__ w,
                                                  u16* __restrict__ oh, u16* __restrict__ ol,
                                                  float* __restrict__ of) {
    int row = blockIdx.x;
    int tid = threadIdx.x;
    const float4 v = ((const float4*)(x + (size_t)row * DM))[tid];
    float ss = v.x * v.x + v.y * v.y + v.z * v.z + v.w * v.w;
    for (int off = 32; off; off >>= 1) ss += __shfl_down(ss, off);
    __shared__ float red[4];
    if ((tid & 63) == 0) red[tid >> 6] = ss;
    __syncthreads();
    float tot = red[0] + red[1] + red[2] + red[3];
    float inv = rsqrtf(tot * (1.0f / DM) + 1e-6f);
    const float4 wv = ((const float4*)w)[tid];
    float o[4];
    o[0] = v.x * inv * wv.x; o[1] = v.y * inv * wv.y;
    o[2] = v.z * inv * wv.z; o[3] = v.w * inv * wv.w;
    if (MODE == 1) {
        float4 f; f.x = o[0]; f.y = o[1]; f.z = o[2]; f.w = o[3];
        ((float4*)(of + (size_t)row * DM))[tid] = f;
        ushort4 hb;
        hb.x = f2b(o[0]); hb.y = f2b(o[1]); hb.z = f2b(o[2]); hb.w = f2b(o[3]);
        ((ushort4*)(oh + (size_t)row * DM))[tid] = hb;
    } else {
        ushort4 hb, lb;
#pragma unroll
        for (int i = 0; i < 4; ++i) {
            u16 h = f2b(o[i]);
            u16 l = f2b(o[i] - b2f(h));
            ((u16*)&hb)[i] = h;
            ((u16*)&lb)[i] = l;
        }
        ((ushort4*)(oh + (size_t)row * DM))[tid] = hb;
        ((ushort4*)(ol + (size_t)row * DM))[tid] = lb;
    }
}

// ---------------- strided fp32 -> hi/lo bf16 split cast ----------------
__global__ __launch_bounds__(256) void scast_k(const float* __restrict__ in, int stride,
                                               int colbase, int cols,
                                               u16* __restrict__ oh, u16* __restrict__ ol) {
    int idx = blockIdx.x * 256 + threadIdx.x;  // octet index
    int cpr = cols >> 3;
    int row = idx / cpr;
    int cc = (idx - row * cpr) << 3;
    const float* p = in + (size_t)row * stride + colbase + cc;
    const float4 a = *(const float4*)p;
    const float4 b = *(const float4*)(p + 4);
    float vv[8] = {a.x, a.y, a.z, a.w, b.x, b.y, b.z, b.w};
    ushort4 h0, h1, l0, l1;
#pragma unroll
    for (int i = 0; i < 8; ++i) {
        u16 h = f2b(vv[i]);
        u16 l = f2b(vv[i] - b2f(h));
        if (i < 4) { ((u16*)&h0)[i] = h; ((u16*)&l0)[i] = l; }
        else       { ((u16*)&h1)[i - 4] = h; ((u16*)&l1)[i - 4] = l; }
    }
    u16* po = oh + (size_t)row * cols + cc;
    u16* pl = ol + (size_t)row * cols + cc;
    *(ushort4*)po = h0; *(ushort4*)(po + 4) = h1;
    *(ushort4*)pl = l0; *(ushort4*)(pl + 4) = l1;
}

// ---------------- V transpose + split: qkv cols 1280..1535 -> vT[(b*256+c)][t] hi/lo ------
__global__ __launch_bounds__(256) void vtrans_k(const float* __restrict__ qkv,
                                                u16* __restrict__ oh, u16* __restrict__ ol) {
    __shared__ float tl[32][33];
    int c0 = blockIdx.x << 5;
    int r0 = blockIdx.y << 5;
    int lr = threadIdx.x >> 3, lc = (threadIdx.x & 7) << 2;
    const float4 v = *(const float4*)&qkv[(size_t)(r0 + lr) * QKVN + 1280 + c0 + lc];
    tl[lr][lc] = v.x; tl[lr][lc + 1] = v.y; tl[lr][lc + 2] = v.z; tl[lr][lc + 3] = v.w;
    __syncthreads();
    int b = r0 >> 11;
    size_t obase = ((size_t)(b * 256 + c0 + lr)) * TSEQ + (r0 & 2047) + lc;
    ushort4 h4, l4;
#pragma unroll
    for (int i = 0; i < 4; ++i) {
        float f = tl[lc + i][lr];
        u16 h = f2b(f);
        u16 l = f2b(f - b2f(h));
        ((u16*)&h4)[i] = h; ((u16*)&l4)[i] = l;
    }
    *(ushort4*)&oh[obase] = h4;
    *(ushort4*)&ol[obase] = l4;
}

// ---------------- weight transpose + split cast: in (R x C) -> out (C x R) hi/lo ----------
__global__ __launch_bounds__(256) void tcast2_k(const float* __restrict__ in,
                                                u16* __restrict__ oh, u16* __restrict__ ol,
                                                int R, int C) {
    __shared__ float tl[32][33];
    int r0 = blockIdx.y << 5, c0 = blockIdx.x << 5;
    int lr = threadIdx.x >> 3, lc = (threadIdx.x & 7) << 2;
    const float4 v = *(const float4*)&in[(size_t)(r0 + lr) * C + c0 + lc];
    tl[lr][lc] = v.x; tl[lr][lc + 1] = v.y; tl[lr][lc + 2] = v.z; tl[lr][lc + 3] = v.w;
    __syncthreads();
    ushort4 h4, l4;
#pragma unroll
    for (int i = 0; i < 4; ++i) {
        float f = tl[lc + i][lr];
        u16 h = f2b(f);
        u16 l = f2b(f - b2f(h));
        ((u16*)&h4)[i] = h; ((u16*)&l4)[i] = l;
    }
    size_t ob = (size_t)(c0 + lr) * R + r0 + lc;
    *(ushort4*)&oh[ob] = h4;
    *(ushort4*)&ol[ob] = l4;
}

// ---------------- plain weight transpose + bf16 cast (MoE weights) ----------------
__global__ __launch_bounds__(256) void tcast_k(const float* __restrict__ in,
                                               u16* __restrict__ out, int R, int C) {
    size_t boff = (size_t)blockIdx.z * R * C;
    in += boff; out += boff;
    __shared__ float tl[32][33];
    int r0 = blockIdx.y << 5, c0 = blockIdx.x << 5;
    int lr = threadIdx.x >> 3, lc = (threadIdx.x & 7) << 2;
    const float4 v = *(const float4*)&in[(size_t)(r0 + lr) * C + c0 + lc];
    tl[lr][lc] = v.x; tl[lr][lc + 1] = v.y; tl[lr][lc + 2] = v.z; tl[lr][lc + 3] = v.w;
    __syncthreads();
    ushort4 o;
    o.x = f2b(tl[lc + 0][lr]); o.y = f2b(tl[lc + 1][lr]);
    o.z = f2b(tl[lc + 2][lr]); o.w = f2b(tl[lc + 3][lr]);
    *(ushort4*)&out[(size_t)(c0 + lr) * R + r0 + lc] = o;
}

// ---------------- RoPE in place on qkv buffer (stride QKVN) ----------------
__global__ void rope2_k(float* __restrict__ x, int nheads, int colbase) {
    int idx = blockIdx.x * blockDim.x + threadIdx.x;
    int total = NTOK * nheads * 32;
    if (idx >= total) return;
    int j = idx & 31;
    int hh = (idx >> 5) % nheads;
    int n = idx / (nheads * 32);
    int t = n & (TSEQ - 1);
    float inv = expf(-(float)j * (0.03125f * logf(10000.0f)));
    float s, c;
    sincosf((float)t * inv, &s, &c);
    float* p = x + (size_t)n * QKVN + colbase + hh * 64 + j * 2;
    float x0 = p[0], x1 = p[1];
    p[0] = x0 * c - x1 * s;
    p[1] = x0 * s + x1 * c;
}

// ---------------- split-bf16 MFMA GEMM: C = A(MxK) @ Bt(NxK)^T (3-term hi/lo) ----------
// EPI: 0 plain f32, 2 + residual R
template <int EPI>
__global__ __launch_bounds__(256) void sgemm_k(const u16* __restrict__ Ah,
                                               const u16* __restrict__ Al,
                                               const u16* __restrict__ Bh,
                                               const u16* __restrict__ Bl,
                                               const float* __restrict__ Rr,
                                               float* __restrict__ C,
                                               int M, int N, int K) {
    __shared__ u16 Ash[128 * 40], Asl[128 * 40], Bsh[128 * 40], Bsl[128 * 40];
    int t = threadIdx.x;
    int l = t & 63, w = t >> 6;
    int wr = w >> 1, wc = w & 1;
    int n0 = blockIdx.x * 128, m0 = blockIdx.y * 128;
    int srow = t >> 2, scol = (t & 3) << 3;
    const u16 *agh[2], *agl[2], *bgh[2], *bgl[2];
#pragma unroll
    for (int i = 0; i < 2; ++i) {
        size_t ao = (size_t)(m0 + i * 64 + srow) * K + scol;
        size_t bo = (size_t)(n0 + i * 64 + srow) * K + scol;
        agh[i] = Ah + ao; agl[i] = Al + ao;
        bgh[i] = Bh + bo; bgl[i] = Bl + bo;
    }
    f4v acc[4][4];
#pragma unroll
    for (int m = 0; m < 4; ++m)
#pragma unroll
        for (int n = 0; n < 4; ++n) acc[m][n] = (f4v)0.0f;
    int kh_ = (l >> 4) << 3;
    for (int k0 = 0; k0 < K; k0 += 32) {
        b8v vah0 = *(const b8v*)(agh[0] + k0);
        b8v vah1 = *(const b8v*)(agh[1] + k0);
        b8v val0 = *(const b8v*)(agl[0] + k0);
        b8v val1 = *(const b8v*)(agl[1] + k0);
        b8v vbh0 = *(const b8v*)(bgh[0] + k0);
        b8v vbh1 = *(const b8v*)(bgh[1] + k0);
        b8v vbl0 = *(const b8v*)(bgl[0] + k0);
        b8v vbl1 = *(const b8v*)(bgl[1] + k0);
        __syncthreads();
        *(b8v*)&Ash[srow * 40 + scol] = vah0;
        *(b8v*)&Ash[(64 + srow) * 40 + scol] = vah1;
        *(b8v*)&Asl[srow * 40 + scol] = val0;
        *(b8v*)&Asl[(64 + srow) * 40 + scol] = val1;
        *(b8v*)&Bsh[srow * 40 + scol] = vbh0;
        *(b8v*)&Bsh[(64 + srow) * 40 + scol] = vbh1;
        *(b8v*)&Bsl[srow * 40 + scol] = vbl0;
        *(b8v*)&Bsl[(64 + srow) * 40 + scol] = vbl1;
        __syncthreads();
        b8v afh[4], afl[4], bfh[4], bfl[4];
#pragma unroll
        for (int m = 0; m < 4; ++m) {
            int ro = (wr * 64 + m * 16 + (l & 15)) * 40 + kh_;
            afh[m] = *(const b8v*)&Ash[ro];
            afl[m] = *(const b8v*)&Asl[ro];
        }
#pragma unroll
        for (int n = 0; n < 4; ++n) {
            int ro = (wc * 64 + n * 16 + (l & 15)) * 40 + kh_;
            bfh[n] = *(const b8v*)&Bsh[ro];
            bfl[n] = *(const b8v*)&Bsl[ro];
        }
#pragma unroll
        for (int m = 0; m < 4; ++m)
#pragma unroll
            for (int n = 0; n < 4; ++n) {
                acc[m][n] = __builtin_amdgcn_mfma_f32_16x16x32_bf16(afl[m], bfh[n], acc[m][n], 0, 0, 0);
                acc[m][n] = __builtin_amdgcn_mfma_f32_16x16x32_bf16(afh[m], bfl[n], acc[m][n], 0, 0, 0);
                acc[m][n] = __builtin_amdgcn_mfma_f32_16x16x32_bf16(afh[m], bfh[n], acc[m][n], 0, 0, 0);
            }
    }
#pragma unroll
    for (int m = 0; m < 4; ++m) {
        int r0l = m0 + wr * 64 + m * 16 + ((l >> 4) << 2);
#pragma unroll
        for (int n = 0; n < 4; ++n) {
            int col = n0 + wc * 64 + n * 16 + (l & 15);
            f4v c = acc[m][n];
#pragma unroll
            for (int j = 0; j < 4; ++j) {
                size_t idx = (size_t)(r0l + j) * N + col;
                float v = c[j];
                if (EPI == 2) v += Rr[idx];
                C[idx] = v;
            }
        }
    }
}

// ---------------- split-bf16 MFMA flash attention (causal GQA) ----------------
// grid: (TSEQ/64, B*NH); 256 thr = 4 waves, wave w owns q rows [q0+16w, q0+16w+16)
__global__ __launch_bounds__(256) void mattn_k(const u16* __restrict__ qh, const u16* __restrict__ ql,
                                               const u16* __restrict__ kh, const u16* __restrict__ kl,
                                               const u16* __restrict__ vth, const u16* __restrict__ vtl,
                                               float* __restrict__ o) {
    __shared__ u16 plds[4][2][16][72];  // [wave][hi/lo][qrow][kvcol], stride 72 kills conflicts
    int t = threadIdx.x, l = t & 63, w = t >> 6;
    int bh = blockIdx.y, b = bh >> 4, h = bh & 15, kvh = h >> 2;
    int q0 = blockIdx.x * 64;
    size_t bT = (size_t)b * TSEQ;
    int lx = l & 15, lg = l >> 4;
    // Q A-fragments: lane row = lx, k = lg*8+j (+32 for d-chunk 1)
    b8v qfh[2], qfl[2];
    {
        size_t qo = (bT + q0 + w * 16 + lx) * DM + h * 64 + lg * 8;
        qfh[0] = *(const b8v*)(qh + qo);
        qfh[1] = *(const b8v*)(qh + qo + 32);
        qfl[0] = *(const b8v*)(ql + qo);
        qfl[1] = *(const b8v*)(ql + qo + 32);
    }
    f4v acc[4];
#pragma unroll
    for (int ht = 0; ht < 4; ++ht) acc[ht] = (f4v)0.0f;
    float m_r[4], l_r[4];
    int qg[4];
#pragma unroll
    for (int r = 0; r < 4; ++r) {
        m_r[r] = -3.0e38f; l_r[r] = 0.0f;
        qg[r] = q0 + w * 16 + lg * 4 + r;
    }
    int ntile = (q0 >> 6) + 1;
    for (int kt = 0; kt < ntile; ++kt) {
        int kv0 = kt << 6;
        f4v s[4];
#pragma unroll
        for (int st = 0; st < 4; ++st) {
            size_t ko = (bT + kv0 + st * 16 + lx) * 256 + kvh * 64 + lg * 8;
            b8v kf0h = *(const b8v*)(kh + ko);
            b8v kf1h = *(const b8v*)(kh + ko + 32);
            b8v kf0l = *(const b8v*)(kl + ko);
            b8v kf1l = *(const b8v*)(kl + ko + 32);
            f4v ss = (f4v)0.0f;
            ss = __builtin_amdgcn_mfma_f32_16x16x32_bf16(qfl[0], kf0h, ss, 0, 0, 0);
            ss = __builtin_amdgcn_mfma_f32_16x16x32_bf16(qfh[0], kf0l, ss, 0, 0, 0);
            ss = __builtin_amdgcn_mfma_f32_16x16x32_bf16(qfh[0], kf0h, ss, 0, 0, 0);
            ss = __builtin_amdgcn_mfma_f32_16x16x32_bf16(qfl[1], kf1h, ss, 0, 0, 0);
            ss = __builtin_amdgcn_mfma_f32_16x16x32_bf16(qfh[1], kf1l, ss, 0, 0, 0);
            ss = __builtin_amdgcn_mfma_f32_16x16x32_bf16(qfh[1], kf1h, ss, 0, 0, 0);
            s[st] = ss;
        }
        float nm[4], sc[4], ps[4];
#pragma unroll
        for (int r = 0; r < 4; ++r) {
            float mx = -3.0e38f;
#pragma unroll
            for (int st = 0; st < 4; ++st) {
                float v = s[st][r] * 0.125f;
                if (kv0 + st * 16 + lx > qg[r]) v = -3.0e38f;
                s[st][r] = v;
                mx = fmaxf(mx, v);
            }
            mx = fmaxf(mx, __shfl_xor(mx, 1));
            mx = fmaxf(mx, __shfl_xor(mx, 2));
            mx = fmaxf(mx, __shfl_xor(mx, 4));
            mx = fmaxf(mx, __shfl_xor(mx, 8));
            nm[r] = fmaxf(m_r[r], mx);
            sc[r] = __expf(m_r[r] - nm[r]);
            m_r[r] = nm[r];
            ps[r] = 0.0f;
        }
#pragma unroll
        for (int st = 0; st < 4; ++st)
#pragma unroll
            for (int r = 0; r < 4; ++r) {
                float p = __expf(s[st][r] - nm[r]);
                ps[r] += p;
                u16 ph = f2b(p);
                u16 pl = f2b(p - b2f(ph));
                plds[w][0][lg * 4 + r][st * 16 + lx] = ph;
                plds[w][1][lg * 4 + r][st * 16 + lx] = pl;
            }
#pragma unroll
        for (int r = 0; r < 4; ++r) {
            float rs = ps[r];
            rs += __shfl_xor(rs, 1);
            rs += __shfl_xor(rs, 2);
            rs += __shfl_xor(rs, 4);
            rs += __shfl_xor(rs, 8);
            l_r[r] = l_r[r] * sc[r] + rs;
#pragma unroll
            for (int ht = 0; ht < 4; ++ht) acc[ht][r] *= sc[r];
        }
        __syncthreads();  // drain P writes (per-wave data; barrier = hard fence)
        b8v pf0h = *(const b8v*)&plds[w][0][lx][lg * 8];
        b8v pf1h = *(const b8v*)&plds[w][0][lx][32 + lg * 8];
        b8v pf0l = *(const b8v*)&plds[w][1][lx][lg * 8];
        b8v pf1l = *(const b8v*)&plds[w][1][lx][32 + lg * 8];
#pragma unroll
        for (int ht = 0; ht < 4; ++ht) {
            size_t vo = ((size_t)(b * 4 + kvh) * 64 + ht * 16 + lx) * TSEQ + kv0 + lg * 8;
            b8v vf0h = *(const b8v*)(vth + vo);
            b8v vf1h = *(const b8v*)(vth + vo + 32);
            b8v vf0l = *(const b8v*)(vtl + vo);
            b8v vf1l = *(const b8v*)(vtl + vo + 32);
            acc[ht] = __builtin_amdgcn_mfma_f32_16x16x32_bf16(pf0l, vf0h, acc[ht], 0, 0, 0);
            acc[ht] = __builtin_amdgcn_mfma_f32_16x16x32_bf16(pf0h, vf0l, acc[ht], 0, 0, 0);
            acc[ht] = __builtin_amdgcn_mfma_f32_16x16x32_bf16(pf0h, vf0h, acc[ht], 0, 0, 0);
            acc[ht] = __builtin_amdgcn_mfma_f32_16x16x32_bf16(pf1l, vf1h, acc[ht], 0, 0, 0);
            acc[ht] = __builtin_amdgcn_mfma_f32_16x16x32_bf16(pf1h, vf1l, acc[ht], 0, 0, 0);
            acc[ht] = __builtin_amdgcn_mfma_f32_16x16x32_bf16(pf1h, vf1h, acc[ht], 0, 0, 0);
        }
        __syncthreads();
    }
#pragma unroll
    for (int ht = 0; ht < 4; ++ht)
#pragma unroll
        for (int r = 0; r < 4; ++r) {
            o[(bT + q0 + w * 16 + lg * 4 + r) * DM + h * 64 + ht * 16 + lx] =
                acc[ht][r] / l_r[r];
        }
}

// ---------------- gate (fp32, unchanged) ----------------
__global__ __launch_bounds__(64) void gate_k(const float* __restrict__ h2,
                                             const float* __restrict__ gw,
                                             const float* __restrict__ gb,
                                             int* __restrict__ top2i,
                                             float* __restrict__ top2w,
                                             int* __restrict__ counts) {
    int n = blockIdx.x;
    int lane = threadIdx.x;
    float acc[8] = {};
    for (int d = lane; d < DM; d += 64) {
        float hv = h2[(size_t)n * DM + d];
        const float4 g0 = ((const float4*)&gw[d * 8])[0];
        const float4 g1 = ((const float4*)&gw[d * 8])[1];
        acc[0] = fmaf(hv, g0.x, acc[0]); acc[1] = fmaf(hv, g0.y, acc[1]);
        acc[2] = fmaf(hv, g0.z, acc[2]); acc[3] = fmaf(hv, g0.w, acc[3]);
        acc[4] = fmaf(hv, g1.x, acc[4]); acc[5] = fmaf(hv, g1.y, acc[5]);
        acc[6] = fmaf(hv, g1.z, acc[6]); acc[7] = fmaf(hv, g1.w, acc[7]);
    }
#pragma unroll
    for (int e = 0; e < 8; ++e)
        for (int off = 32; off; off >>= 1) acc[e] += __shfl_down(acc[e], off);
    if (lane == 0) {
        float s[8];
#pragma unroll
        for (int e = 0; e < 8; ++e) s[e] = 1.0f / (1.0f + expf(-acc[e])) + gb[e];
        int i0 = 0;
#pragma unroll
        for (int e = 1; e < 8; ++e) if (s[e] > s[i0]) i0 = e;
        int i1 = (i0 == 0) ? 1 : 0;
#pragma unroll
        for (int e = 0; e < 8; ++e) if (e != i0 && s[e] > s[i1]) i1 = e;
        float w0 = s[i0], w1 = s[i1];
        float norm = 1.0f / (w0 + w1 + 1e-20f);
        top2i[n * 2] = i0; top2i[n * 2 + 1] = i1;
        top2w[n * 2] = w0 * norm; top2w[n * 2 + 1] = w1 * norm;
        atomicAdd(&counts[i0], 1);
        atomicAdd(&counts[i1], 1);
    }
}

__global__ void zero16_k(int* p) { if (threadIdx.x < 16) p[threadIdx.x] = 0; }

__global__ void scan_k(const int* __restrict__ counts, int* __restrict__ segs) {
    if (threadIdx.x == 0) {
        segs[0] = 0;
        for (int e = 0; e < NE; ++e) segs[e + 1] = segs[e] + counts[e];
    }
}

__global__ void scatter_k(const int* __restrict__ top2i, const float* __restrict__ top2w,
                          const int* __restrict__ segs, int* __restrict__ cursor,
                          int* __restrict__ list, float* __restrict__ wslot,
                          int* __restrict__ slot_of) {
    int idx = blockIdx.x * blockDim.x + threadIdx.x;
    if (idx >= NTOK * 2) return;
    int e = top2i[idx];
    int pos = segs[e] + atomicAdd(&cursor[e], 1);
    list[pos] = idx >> 1;
    wslot[pos] = top2w[idx];
    slot_of[idx] = pos;
}

// ---------------- bf16 MFMA GEMM (MoE path, unchanged from round 2) ----------------
template <int EPI, int MOE, int GATHER>
__global__ __launch_bounds__(256) void mgemm_k(const u16* __restrict__ A,
                                               const u16* __restrict__ Bt,
                                               const float* __restrict__ R,
                                               const float* __restrict__ wslot,
                                               const int* __restrict__ list,
                                               const int* __restrict__ segs,
                                               float* __restrict__ Cf,
                                               u16* __restrict__ Cb,
                                               int M, int N, int K) {
    __shared__ u16 As[128 * 40];
    __shared__ u16 Bs[128 * 40];
    int e = MOE ? blockIdx.z : 0;
    int base = 0, cnt = M;
    if (MOE) { base = segs[e]; cnt = segs[e + 1] - base; }
    int m0 = blockIdx.y * 128;
    if (m0 >= cnt) return;
    int n0 = blockIdx.x * 128;
    const u16* Bte = Bt + (size_t)e * N * K;
    int t = threadIdx.x;
    int l = t & 63, w = t >> 6;
    int wr = w >> 1, wc = w & 1;
    int srow = t >> 2, scol = (t & 3) << 3;
    const u16* ag[2];
    const u16* bg[2];
#pragma unroll
    for (int i = 0; i < 2; ++i) {
        int r = m0 + i * 64 + srow;
        int ar;
        if (MOE) {
            int rc = r < cnt ? r : cnt - 1;
            ar = GATHER ? list[base + rc] : base + rc;
        } else {
            ar = r;
        }
        ag[i] = A + (size_t)ar * K + scol;
        bg[i] = Bte + (size_t)(n0 + i * 64 + srow) * K + scol;
    }
    f4v acc[4][4];
#pragma unroll
    for (int m = 0; m < 4; ++m)
#pragma unroll
        for (int n = 0; n < 4; ++n) acc[m][n] = (f4v)0.0f;
    int kh = (l >> 4) << 3;
    for (int k0 = 0; k0 < K; k0 += 32) {
        b8v va0 = *(const b8v*)(ag[0] + k0);
        b8v va1 = *(const b8v*)(ag[1] + k0);
        b8v vb0 = *(const b8v*)(bg[0] + k0);
        b8v vb1 = *(const b8v*)(bg[1] + k0);
        __syncthreads();
        *(b8v*)&As[srow * 40 + scol] = va0;
        *(b8v*)&As[(64 + srow) * 40 + scol] = va1;
        *(b8v*)&Bs[srow * 40 + scol] = vb0;
        *(b8v*)&Bs[(64 + srow) * 40 + scol] = vb1;
        __syncthreads();
        b8v af[4], bf[4];
#pragma unroll
        for (int m = 0; m < 4; ++m)
            af[m] = *(const b8v*)&As[(wr * 64 + m * 16 + (l & 15)) * 40 + kh];
#pragma unroll
        for (int n = 0; n < 4; ++n)
            bf[n] = *(const b8v*)&Bs[(wc * 64 + n * 16 + (l & 15)) * 40 + kh];
#pragma unroll
        for (int m = 0; m < 4; ++m)
#pragma unroll
            for (int n = 0; n < 4; ++n)
                acc[m][n] = __builtin_amdgcn_mfma_f32_16x16x32_bf16(af[m], bf[n], acc[m][n], 0, 0, 0);
    }
#pragma unroll
    for (int m = 0; m < 4; ++m) {
        int r0l = m0 + wr * 64 + m * 16 + ((l >> 4) << 2);
#pragma unroll
        for (int n = 0; n < 4; ++n) {
            int col = n0 + wc * 64 + n * 16 + (l & 15);
            f4v c = acc[m][n];
#pragma unroll
            for (int j = 0; j < 4; ++j) {
                int row = r0l + j;
                if (MOE && row >= cnt) continue;
                float v = c[j];
                if (EPI == 1) {
                    v = silu_f(v);
                    Cb[(size_t)(base + row) * N + col] = f2b(v);
                } else if (EPI == 2) {
                    size_t idx = (size_t)row * N + col;
                    Cf[idx] = v + R[idx];
                } else if (EPI == 3) {
                    Cf[(size_t)(base + row) * N + col] = v * wslot[base + row];
                } else {
                    Cf[(size_t)row * N + col] = v;
                }
            }
        }
    }
}

// ---------------- combine ----------------
__global__ __launch_bounds__(256) void combine_k(const float* __restrict__ eout,
                                                 const int* __restrict__ slot_of,
                                                 float* __restrict__ out) {
    int idx = blockIdx.x * blockDim.x + threadIdx.x;
    int n = idx >> 8;
    int c = idx & 255;
    const float4 a = ((const float4*)(eout + (size_t)slot_of[n * 2] * DM))[c];
    const float4 b = ((const float4*)(eout + (size_t)slot_of[n * 2 + 1] * DM))[c];
    float4 o = ((float4*)out)[idx];
    o.x += a.x + b.x; o.y += a.y + b.y; o.z += a.z + b.z; o.w += a.w + b.w;
    ((float4*)out)[idx] = o;
}

extern "C" void kernel_launch(void* const* d_in, const int* in_sizes, int n_in,
                              void* d_out, int out_size, void* d_ws, size_t ws_size,
                              hipStream_t stream) {
    (void)in_sizes; (void)n_in; (void)out_size; (void)ws_size;
    const float* x   = (const float*)d_in[0];
    const float* anw = (const float*)d_in[1];
    const float* wq  = (const float*)d_in[2];
    const float* wk  = (const float*)d_in[3];
    const float* wv  = (const float*)d_in[4];
    const float* wo  = (const float*)d_in[5];
    const float* fnw = (const float*)d_in[6];
    const float* gw  = (const float*)d_in[7];
    const float* gb  = (const float*)d_in[8];
    const float* ew1 = (const float*)d_in[9];
    const float* ew2 = (const float*)d_in[10];
    const float* sw1 = (const float*)d_in[11];
    const float* sw2 = (const float*)d_in[12];
    float* out = (float*)d_out;

#define WSOFF(mb) ((char*)d_ws + (size_t)(mb) * 1048576)
    // weights (persistent): 0..82 MB
    u16* qkvT_h = (u16*)WSOFF(0);    // 1536x1024
    u16* qkvT_l = (u16*)WSOFF(3);
    u16* woT_h  = (u16*)WSOFF(6);    // 1024x1024
    u16* woT_l  = (u16*)WSOFF(8);
    u16* sw1t   = (u16*)WSOFF(10);   // 2048x1024
    u16* sw2t   = (u16*)WSOFF(14);   // 1024x2048
    u16* ew1t   = (u16*)WSOFF(18);   // 8 x 2048x1024
    u16* ew2t   = (u16*)WSOFF(50);   // 8 x 1024x2048
    // activations (lifetime-overlapped):
    float* qkv  = (float*)WSOFF(82);   // 4096x1536 f32 (82..106); dead after vtrans
    float* ao   = (float*)WSOFF(82);   // attn_out f32 (82..98); dead after scast_ao
    float* h2f  = (float*)WSOFF(82);   // h2 f32 (82..98)
    u16* h_hi   = (u16*)WSOFF(106);    // h split (106..122); dead after QKV gemm
    u16* h_lo   = (u16*)WSOFF(114);
    u16* ao_hi  = (u16*)WSOFF(106);    // ao split (106..122); dead after Wo gemm
    u16* ao_lo  = (u16*)WSOFF(114);
    u16* q_hi   = (u16*)WSOFF(122);    // q split (122..138); dead after attn
    u16* q_lo   = (u16*)WSOFF(130);
    u16* k_hi   = (u16*)WSOFF(138);    // k split (138..142)
    u16* k_lo   = (u16*)WSOFF(140);
    u16* vT_hi  = (u16*)WSOFF(142);    // vT split (142..146)
    u16* vT_lo  = (u16*)WSOFF(144);
    float* x1   = (float*)WSOFF(146);  // x1 f32 (146..162); dead after shared2
    u16* h2b    = (u16*)WSOFF(162);    // h2 bf16 (162..170); dead after moe_w1
    u16* midb   = (u16*)WSOFF(170);    // shared mid bf16 (170..186); dead after shared2
    u16* hmidb  = (u16*)WSOFF(122);    // routed mid bf16 (122..154); after shared2
    float* eoutb = (float*)WSOFF(154); // expert out f32 (154..186)
    int* meta0  = (int*)WSOFF(186);
    int*   top2i  = meta0;
    float* top2w  = (float*)(meta0 + 8192);
    int*   counts = meta0 + 16384;
    int*   cursor = meta0 + 16392;
    int*   segs   = meta0 + 16400;
    int*   list   = meta0 + 16416;
    float* wslot  = (float*)(meta0 + 16416 + 8192);
    int*   slot_of = meta0 + 16416 + 16384;

    // ---- weight prep ----
    tcast2_k<<<dim3(32, 32), 256, 0, stream>>>(wq, qkvT_h, qkvT_l, DM, 1024);
    tcast2_k<<<dim3(8, 32), 256, 0, stream>>>(wk, qkvT_h + 1024 * 1024, qkvT_l + 1024 * 1024, DM, 256);
    tcast2_k<<<dim3(8, 32), 256, 0, stream>>>(wv, qkvT_h + 1280 * 1024, qkvT_l + 1280 * 1024, DM, 256);
    tcast2_k<<<dim3(32, 32), 256, 0, stream>>>(wo, woT_h, woT_l, DM, DM);
    tcast_k<<<dim3(NFF / 32, DM / 32, 1), 256, 0, stream>>>(sw1, sw1t, DM, NFF);
    tcast_k<<<dim3(DM / 32, NFF / 32, 1), 256, 0, stream>>>(sw2, sw2t, NFF, DM);
    tcast_k<<<dim3(NFF / 32, DM / 32, NE), 256, 0, stream>>>(ew1, ew1t, DM, NFF);
    tcast_k<<<dim3(DM / 32, NFF / 32, NE), 256, 0, stream>>>(ew2, ew2t, NFF, DM);

    // 1. h = rmsnorm(x) -> hi/lo split
    rmsnorm2_k<0><<<NTOK, 256, 0, stream>>>(x, anw, h_hi, h_lo, nullptr);
    // 2. fused QKV projection (split MFMA) -> qkv f32
    sgemm_k<0><<<dim3(QKVN / 128, NTOK / 128), 256, 0, stream>>>(
        h_hi, h_lo, qkvT_h, qkvT_l, nullptr, qkv, NTOK, QKVN, DM);
    // 3. RoPE on q and k parts
    rope2_k<<<(NTOK * NH * 32 + 255) / 256, 256, 0, stream>>>(qkv, NH, 0);
    rope2_k<<<(NTOK * NKV * 32 + 255) / 256, 256, 0, stream>>>(qkv, NKV, 1024);
    // 3.5 split casts for attention
    scast_k<<<2048, 256, 0, stream>>>(qkv, QKVN, 0, 1024, q_hi, q_lo);
    scast_k<<<512, 256, 0, stream>>>(qkv, QKVN, 1024, 256, k_hi, k_lo);
    vtrans_k<<<dim3(8, 128), 256, 0, stream>>>(qkv, vT_hi, vT_lo);
    // 4. attention -> ao (f32)
    mattn_k<<<dim3(TSEQ / 64, 32), 256, 0, stream>>>(q_hi, q_lo, k_hi, k_lo, vT_hi, vT_lo, ao);
    // 5. x1 = ao @ wo + x
    scast_k<<<2048, 256, 0, stream>>>(ao, DM, 0, DM, ao_hi, ao_lo);
    sgemm_k<2><<<dim3(DM / 128, NTOK / 128), 256, 0, stream>>>(
        ao_hi, ao_lo, woT_h, woT_l, x, x1, NTOK, DM, DM);
    // 6. h2 = rmsnorm(x1) -> f32 (gate) + bf16 (MoE)
    rmsnorm2_k<1><<<NTOK, 256, 0, stream>>>(x1, fnw, h2b, nullptr, h2f);
    // 7. gate + routing
    zero16_k<<<1, 64, 0, stream>>>(counts);
    gate_k<<<NTOK, 64, 0, stream>>>(h2f, gw, gb, top2i, top2w, counts);
    scan_k<<<1, 1, 0, stream>>>(counts, segs);
    scatter_k<<<32, 256, 0, stream>>>(top2i, top2w, segs, cursor, list, wslot, slot_of);
    // 8. shared expert
    mgemm_k<1, 0, 0><<<dim3(NFF / 128, NTOK / 128, 1), 256, 0, stream>>>(
        h2b, sw1t, nullptr, nullptr, nullptr, nullptr, nullptr, midb, NTOK, NFF, DM);
    mgemm_k<2, 0, 0><<<dim3(DM / 128, NTOK / 128, 1), 256, 0, stream>>>(
        midb, sw2t, x1, nullptr, nullptr, nullptr, out, nullptr, NTOK, DM, NFF);
    // 9. routed experts
    mgemm_k<1, 1, 1><<<dim3(NFF / 128, NTOK / 128, NE), 256, 0, stream>>>(
        h2b, ew1t, nullptr, nullptr, list, segs, nullptr, hmidb, NTOK, NFF, DM);
    mgemm_k<3, 1, 0><<<dim3(DM / 128, NTOK / 128, NE), 256, 0, stream>>>(
        hmidb, ew2t, nullptr, wslot, nullptr, segs, eoutb, nullptr, 2 * NTOK, DM, NFF);
    combine_k<<<NTOK, 256, 0, stream>>>(eoutb, slot_of, out);
#undef WSOFF
}

// Round 5
// 1028.919 us; speedup vs baseline: 2.8065x; 1.2094x over previous
//
#include <hip/hip_runtime.h>
#include <math.h>

#define NTOK 4096
#define DM 1024
#define TSEQ 2048
#define NH 16
#define NKV 4
#define HDIM 64
#define NE 8
#define NFF 2048
#define QKVN 1536

typedef float f4v __attribute__((ext_vector_type(4)));
typedef short b8v __attribute__((ext_vector_type(8)));
typedef unsigned short u16;

__device__ __forceinline__ float silu_f(float v) { return v / (1.0f + expf(-v)); }

__device__ __forceinline__ u16 f2b(float f) {
    union { float f; unsigned u; } x{f};
    unsigned r = (x.u + 0x7FFFu + ((x.u >> 16) & 1u)) >> 16;
    return (u16)r;
}
__device__ __forceinline__ float b2f(u16 b) {
    union { unsigned u; float f; } x;
    x.u = ((unsigned)b) << 16;
    return x.f;
}

// ---------------- RMSNorm, MODE 0: write hi/lo bf16 split; MODE 1: write f32 + plain bf16 ----
template <int MODE>
__global__ __launch_bounds__(256) void rmsnorm2_k(const float* __restrict__ x,
                                                  const float* __restrict__ w,
                                                  u16* __restrict__ oh, u16* __restrict__ ol,
                                                  float* __restrict__ of) {
    int row = blockIdx.x;
    int tid = threadIdx.x;
    const float4 v = ((const float4*)(x + (size_t)row * DM))[tid];
    float ss = v.x * v.x + v.y * v.y + v.z * v.z + v.w * v.w;
    for (int off = 32; off; off >>= 1) ss += __shfl_down(ss, off);
    __shared__ float red[4];
    if ((tid & 63) == 0) red[tid >> 6] = ss;
    __syncthreads();
    float tot = red[0] + red[1] + red[2] + red[3];
    float inv = rsqrtf(tot * (1.0f / DM) + 1e-6f);
    const float4 wv = ((const float4*)w)[tid];
    float o[4];
    o[0] = v.x * inv * wv.x; o[1] = v.y * inv * wv.y;
    o[2] = v.z * inv * wv.z; o[3] = v.w * inv * wv.w;
    if (MODE == 1) {
        float4 f; f.x = o[0]; f.y = o[1]; f.z = o[2]; f.w = o[3];
        ((float4*)(of + (size_t)row * DM))[tid] = f;
        ushort4 hb;
        hb.x = f2b(o[0]); hb.y = f2b(o[1]); hb.z = f2b(o[2]); hb.w = f2b(o[3]);
        ((ushort4*)(oh + (size_t)row * DM))[tid] = hb;
    } else {
        ushort4 hb, lb;
#pragma unroll
        for (int i = 0; i < 4; ++i) {
            u16 h = f2b(o[i]);
            u16 l = f2b(o[i] - b2f(h));
            ((u16*)&hb)[i] = h;
            ((u16*)&lb)[i] = l;
        }
        ((ushort4*)(oh + (size_t)row * DM))[tid] = hb;
        ((ushort4*)(ol + (size_t)row * DM))[tid] = lb;
    }
}

// ---------------- strided fp32 -> hi/lo bf16 split cast ----------------
__global__ __launch_bounds__(256) void scast_k(const float* __restrict__ in, int stride,
                                               int colbase, int cols,
                                               u16* __restrict__ oh, u16* __restrict__ ol) {
    int idx = blockIdx.x * 256 + threadIdx.x;  // octet index
    int cpr = cols >> 3;
    int row = idx / cpr;
    int cc = (idx - row * cpr) << 3;
    const float* p = in + (size_t)row * stride + colbase + cc;
    const float4 a = *(const float4*)p;
    const float4 b = *(const float4*)(p + 4);
    float vv[8] = {a.x, a.y, a.z, a.w, b.x, b.y, b.z, b.w};
    ushort4 h0, h1, l0, l1;
#pragma unroll
    for (int i = 0; i < 8; ++i) {
        u16 h = f2b(vv[i]);
        u16 l = f2b(vv[i] - b2f(h));
        if (i < 4) { ((u16*)&h0)[i] = h; ((u16*)&l0)[i] = l; }
        else       { ((u16*)&h1)[i - 4] = h; ((u16*)&l1)[i - 4] = l; }
    }
    u16* po = oh + (size_t)row * cols + cc;
    u16* pl = ol + (size_t)row * cols + cc;
    *(ushort4*)po = h0; *(ushort4*)(po + 4) = h1;
    *(ushort4*)pl = l0; *(ushort4*)(pl + 4) = l1;
}

// ---------------- V transpose + split: qkv cols 1280..1535 -> vT[(b*256+c)][t] hi/lo ------
__global__ __launch_bounds__(256) void vtrans_k(const float* __restrict__ qkv,
                                                u16* __restrict__ oh, u16* __restrict__ ol) {
    __shared__ float tl[32][33];
    int c0 = blockIdx.x << 5;
    int r0 = blockIdx.y << 5;
    int lr = threadIdx.x >> 3, lc = (threadIdx.x & 7) << 2;
    const float4 v = *(const float4*)&qkv[(size_t)(r0 + lr) * QKVN + 1280 + c0 + lc];
    tl[lr][lc] = v.x; tl[lr][lc + 1] = v.y; tl[lr][lc + 2] = v.z; tl[lr][lc + 3] = v.w;
    __syncthreads();
    int b = r0 >> 11;
    size_t obase = ((size_t)(b * 256 + c0 + lr)) * TSEQ + (r0 & 2047) + lc;
    ushort4 h4, l4;
#pragma unroll
    for (int i = 0; i < 4; ++i) {
        float f = tl[lc + i][lr];
        u16 h = f2b(f);
        u16 l = f2b(f - b2f(h));
        ((u16*)&h4)[i] = h; ((u16*)&l4)[i] = l;
    }
    *(ushort4*)&oh[obase] = h4;
    *(ushort4*)&ol[obase] = l4;
}

// ---------------- weight transpose + split cast: in (R x C) -> out (C x R) hi/lo ----------
__global__ __launch_bounds__(256) void tcast2_k(const float* __restrict__ in,
                                                u16* __restrict__ oh, u16* __restrict__ ol,
                                                int R, int C) {
    __shared__ float tl[32][33];
    int r0 = blockIdx.y << 5, c0 = blockIdx.x << 5;
    int lr = threadIdx.x >> 3, lc = (threadIdx.x & 7) << 2;
    const float4 v = *(const float4*)&in[(size_t)(r0 + lr) * C + c0 + lc];
    tl[lr][lc] = v.x; tl[lr][lc + 1] = v.y; tl[lr][lc + 2] = v.z; tl[lr][lc + 3] = v.w;
    __syncthreads();
    ushort4 h4, l4;
#pragma unroll
    for (int i = 0; i < 4; ++i) {
        float f = tl[lc + i][lr];
        u16 h = f2b(f);
        u16 l = f2b(f - b2f(h));
        ((u16*)&h4)[i] = h; ((u16*)&l4)[i] = l;
    }
    size_t ob = (size_t)(c0 + lr) * R + r0 + lc;
    *(ushort4*)&oh[ob] = h4;
    *(ushort4*)&ol[ob] = l4;
}

// ---------------- plain weight transpose + bf16 cast (MoE weights) ----------------
__global__ __launch_bounds__(256) void tcast_k(const float* __restrict__ in,
                                               u16* __restrict__ out, int R, int C) {
    size_t boff = (size_t)blockIdx.z * R * C;
    in += boff; out += boff;
    __shared__ float tl[32][33];
    int r0 = blockIdx.y << 5, c0 = blockIdx.x << 5;
    int lr = threadIdx.x >> 3, lc = (threadIdx.x & 7) << 2;
    const float4 v = *(const float4*)&in[(size_t)(r0 + lr) * C + c0 + lc];
    tl[lr][lc] = v.x; tl[lr][lc + 1] = v.y; tl[lr][lc + 2] = v.z; tl[lr][lc + 3] = v.w;
    __syncthreads();
    ushort4 o;
    o.x = f2b(tl[lc + 0][lr]); o.y = f2b(tl[lc + 1][lr]);
    o.z = f2b(tl[lc + 2][lr]); o.w = f2b(tl[lc + 3][lr]);
    *(ushort4*)&out[(size_t)(c0 + lr) * R + r0 + lc] = o;
}

// ---------------- RoPE in place on qkv buffer (stride QKVN) ----------------
__global__ void rope2_k(float* __restrict__ x, int nheads, int colbase) {
    int idx = blockIdx.x * blockDim.x + threadIdx.x;
    int total = NTOK * nheads * 32;
    if (idx >= total) return;
    int j = idx & 31;
    int hh = (idx >> 5) % nheads;
    int n = idx / (nheads * 32);
    int t = n & (TSEQ - 1);
    float inv = expf(-(float)j * (0.03125f * logf(10000.0f)));
    float s, c;
    sincosf((float)t * inv, &s, &c);
    float* p = x + (size_t)n * QKVN + colbase + hh * 64 + j * 2;
    float x0 = p[0], x1 = p[1];
    p[0] = x0 * c - x1 * s;
    p[1] = x0 * s + x1 * c;
}

// ---------------- split-bf16 MFMA GEMM: C = A(MxK) @ Bt(NxK)^T (3-term hi/lo) ----------
template <int EPI>
__global__ __launch_bounds__(256) void sgemm_k(const u16* __restrict__ Ah,
                                               const u16* __restrict__ Al,
                                               const u16* __restrict__ Bh,
                                               const u16* __restrict__ Bl,
                                               const float* __restrict__ Rr,
                                               float* __restrict__ C,
                                               int M, int N, int K) {
    __shared__ u16 Ash[128 * 40], Asl[128 * 40], Bsh[128 * 40], Bsl[128 * 40];
    int t = threadIdx.x;
    int l = t & 63, w = t >> 6;
    int wr = w >> 1, wc = w & 1;
    int n0 = blockIdx.x * 128, m0 = blockIdx.y * 128;
    int srow = t >> 2, scol = (t & 3) << 3;
    const u16 *agh[2], *agl[2], *bgh[2], *bgl[2];
#pragma unroll
    for (int i = 0; i < 2; ++i) {
        size_t ao = (size_t)(m0 + i * 64 + srow) * K + scol;
        size_t bo = (size_t)(n0 + i * 64 + srow) * K + scol;
        agh[i] = Ah + ao; agl[i] = Al + ao;
        bgh[i] = Bh + bo; bgl[i] = Bl + bo;
    }
    f4v acc[4][4];
#pragma unroll
    for (int m = 0; m < 4; ++m)
#pragma unroll
        for (int n = 0; n < 4; ++n) acc[m][n] = (f4v)0.0f;
    int kh_ = (l >> 4) << 3;
    for (int k0 = 0; k0 < K; k0 += 32) {
        b8v vah0 = *(const b8v*)(agh[0] + k0);
        b8v vah1 = *(const b8v*)(agh[1] + k0);
        b8v val0 = *(const b8v*)(agl[0] + k0);
        b8v val1 = *(const b8v*)(agl[1] + k0);
        b8v vbh0 = *(const b8v*)(bgh[0] + k0);
        b8v vbh1 = *(const b8v*)(bgh[1] + k0);
        b8v vbl0 = *(const b8v*)(bgl[0] + k0);
        b8v vbl1 = *(const b8v*)(bgl[1] + k0);
        __syncthreads();
        *(b8v*)&Ash[srow * 40 + scol] = vah0;
        *(b8v*)&Ash[(64 + srow) * 40 + scol] = vah1;
        *(b8v*)&Asl[srow * 40 + scol] = val0;
        *(b8v*)&Asl[(64 + srow) * 40 + scol] = val1;
        *(b8v*)&Bsh[srow * 40 + scol] = vbh0;
        *(b8v*)&Bsh[(64 + srow) * 40 + scol] = vbh1;
        *(b8v*)&Bsl[srow * 40 + scol] = vbl0;
        *(b8v*)&Bsl[(64 + srow) * 40 + scol] = vbl1;
        __syncthreads();
        b8v afh[4], afl[4], bfh[4], bfl[4];
#pragma unroll
        for (int m = 0; m < 4; ++m) {
            int ro = (wr * 64 + m * 16 + (l & 15)) * 40 + kh_;
            afh[m] = *(const b8v*)&Ash[ro];
            afl[m] = *(const b8v*)&Asl[ro];
        }
#pragma unroll
        for (int n = 0; n < 4; ++n) {
            int ro = (wc * 64 + n * 16 + (l & 15)) * 40 + kh_;
            bfh[n] = *(const b8v*)&Bsh[ro];
            bfl[n] = *(const b8v*)&Bsl[ro];
        }
#pragma unroll
        for (int m = 0; m < 4; ++m)
#pragma unroll
            for (int n = 0; n < 4; ++n) {
                acc[m][n] = __builtin_amdgcn_mfma_f32_16x16x32_bf16(afl[m], bfh[n], acc[m][n], 0, 0, 0);
                acc[m][n] = __builtin_amdgcn_mfma_f32_16x16x32_bf16(afh[m], bfl[n], acc[m][n], 0, 0, 0);
                acc[m][n] = __builtin_amdgcn_mfma_f32_16x16x32_bf16(afh[m], bfh[n], acc[m][n], 0, 0, 0);
            }
    }
#pragma unroll
    for (int m = 0; m < 4; ++m) {
        int r0l = m0 + wr * 64 + m * 16 + ((l >> 4) << 2);
#pragma unroll
        for (int n = 0; n < 4; ++n) {
            int col = n0 + wc * 64 + n * 16 + (l & 15);
            f4v c = acc[m][n];
#pragma unroll
            for (int j = 0; j < 4; ++j) {
                size_t idx = (size_t)(r0l + j) * N + col;
                float v = c[j];
                if (EPI == 2) v += Rr[idx];
                C[idx] = v;
            }
        }
    }
}

// ---------------- split-bf16 MFMA flash attention v2b ----------------
// Barrier-free across waves; P LDS round-trip ordered by an explicit
// wave-local fence (__threadfence_block -> s_waitcnt lgkmcnt(0)) + sched_barrier.
// LDS element type == fragment element type (short) for consistent aliasing.
// grid: (TSEQ/128, B*NH) = (16, 32); block does q-tiles bx and 31-bx (uniform 33 kv-tiles).
__global__ __launch_bounds__(256) void mattn_k(const u16* __restrict__ qh, const u16* __restrict__ ql,
                                               const u16* __restrict__ kh, const u16* __restrict__ kl,
                                               const u16* __restrict__ vth, const u16* __restrict__ vtl,
                                               float* __restrict__ o) {
    __shared__ short plds[4][2][16][72];
    int t = threadIdx.x, l = t & 63, w = t >> 6;
    int bh = blockIdx.y, b = bh >> 4, h = bh & 15, kvh = h >> 2;
    size_t bT = (size_t)b * TSEQ;
    int lx = l & 15, lg = l >> 4;
#pragma unroll
    for (int half = 0; half < 2; ++half) {
        int qt = half ? (31 - blockIdx.x) : blockIdx.x;
        int q0 = qt * 64;
        b8v qfh[2], qfl[2];
        {
            size_t qo = (bT + q0 + w * 16 + lx) * DM + h * 64 + lg * 8;
            qfh[0] = *(const b8v*)(qh + qo);
            qfh[1] = *(const b8v*)(qh + qo + 32);
            qfl[0] = *(const b8v*)(ql + qo);
            qfl[1] = *(const b8v*)(ql + qo + 32);
        }
        f4v acc[4];
#pragma unroll
        for (int ht = 0; ht < 4; ++ht) acc[ht] = (f4v)0.0f;
        float l_r[4] = {0.0f, 0.0f, 0.0f, 0.0f};
        int qg[4];
#pragma unroll
        for (int r = 0; r < 4; ++r) qg[r] = q0 + w * 16 + lg * 4 + r;
        int ntile = qt + 1;
        for (int kt = 0; kt < ntile; ++kt) {
            int kv0 = kt << 6;
            // ---- QK^T (K frags straight from L2) ----
            f4v s[4];
#pragma unroll
            for (int st = 0; st < 4; ++st) {
                size_t ko = (bT + kv0 + st * 16 + lx) * 256 + kvh * 64 + lg * 8;
                b8v kf0h = *(const b8v*)(kh + ko);
                b8v kf1h = *(const b8v*)(kh + ko + 32);
                b8v kf0l = *(const b8v*)(kl + ko);
                b8v kf1l = *(const b8v*)(kl + ko + 32);
                f4v ss = (f4v)0.0f;
                ss = __builtin_amdgcn_mfma_f32_16x16x32_bf16(qfl[0], kf0h, ss, 0, 0, 0);
                ss = __builtin_amdgcn_mfma_f32_16x16x32_bf16(qfh[0], kf0l, ss, 0, 0, 0);
                ss = __builtin_amdgcn_mfma_f32_16x16x32_bf16(qfh[0], kf0h, ss, 0, 0, 0);
                ss = __builtin_amdgcn_mfma_f32_16x16x32_bf16(qfl[1], kf1h, ss, 0, 0, 0);
                ss = __builtin_amdgcn_mfma_f32_16x16x32_bf16(qfh[1], kf1l, ss, 0, 0, 0);
                ss = __builtin_amdgcn_mfma_f32_16x16x32_bf16(qfh[1], kf1h, ss, 0, 0, 0);
                s[st] = ss;
            }
            // ---- issue V loads now; latency hides under softmax VALU ----
            b8v vh0[4], vh1[4], vl0[4], vl1[4];
#pragma unroll
            for (int ht = 0; ht < 4; ++ht) {
                size_t vo = ((size_t)(b * 4 + kvh) * 64 + ht * 16 + lx) * TSEQ + kv0 + lg * 8;
                vh0[ht] = *(const b8v*)(vth + vo);
                vh1[ht] = *(const b8v*)(vth + vo + 32);
                vl0[ht] = *(const b8v*)(vtl + vo);
                vl1[ht] = *(const b8v*)(vtl + vo + 32);
            }
            // ---- softmax, m == 0 (scores bounded; clamp for safety) ----
#pragma unroll
            for (int st = 0; st < 4; ++st)
#pragma unroll
                for (int r = 0; r < 4; ++r) {
                    float v = s[st][r] * 0.125f;
                    float p = (kv0 + st * 16 + lx > qg[r])
                                  ? 0.0f
                                  : __expf(fminf(v, 60.0f));
                    l_r[r] += p;
                    u16 ph = f2b(p);
                    u16 pl = f2b(p - b2f(ph));
                    plds[w][0][lg * 4 + r][st * 16 + lx] = (short)ph;
                    plds[w][1][lg * 4 + r][st * 16 + lx] = (short)pl;
                }
            // wave-local fence: drain LDS writes before fragment reads (no block barrier)
            __threadfence_block();
            __builtin_amdgcn_sched_barrier(0);
            b8v pf0h = *(const b8v*)&plds[w][0][lx][lg * 8];
            b8v pf1h = *(const b8v*)&plds[w][0][lx][32 + lg * 8];
            b8v pf0l = *(const b8v*)&plds[w][1][lx][lg * 8];
            b8v pf1l = *(const b8v*)&plds[w][1][lx][32 + lg * 8];
            __builtin_amdgcn_sched_barrier(0);
#pragma unroll
            for (int ht = 0; ht < 4; ++ht) {
                acc[ht] = __builtin_amdgcn_mfma_f32_16x16x32_bf16(pf0l, vh0[ht], acc[ht], 0, 0, 0);
                acc[ht] = __builtin_amdgcn_mfma_f32_16x16x32_bf16(pf0h, vl0[ht], acc[ht], 0, 0, 0);
                acc[ht] = __builtin_amdgcn_mfma_f32_16x16x32_bf16(pf0h, vh0[ht], acc[ht], 0, 0, 0);
                acc[ht] = __builtin_amdgcn_mfma_f32_16x16x32_bf16(pf1l, vh1[ht], acc[ht], 0, 0, 0);
                acc[ht] = __builtin_amdgcn_mfma_f32_16x16x32_bf16(pf1h, vl1[ht], acc[ht], 0, 0, 0);
                acc[ht] = __builtin_amdgcn_mfma_f32_16x16x32_bf16(pf1h, vh1[ht], acc[ht], 0, 0, 0);
            }
        }
        // ---- epilogue: reduce row sums across the 16-lane group, write O ----
#pragma unroll
        for (int r = 0; r < 4; ++r) {
            float rs = l_r[r];
            rs += __shfl_xor(rs, 1);
            rs += __shfl_xor(rs, 2);
            rs += __shfl_xor(rs, 4);
            rs += __shfl_xor(rs, 8);
            float rinv = 1.0f / rs;
#pragma unroll
            for (int ht = 0; ht < 4; ++ht) {
                o[(bT + q0 + w * 16 + lg * 4 + r) * DM + h * 64 + ht * 16 + lx] =
                    acc[ht][r] * rinv;
            }
        }
    }
}

// ---------------- gate (fp32, unchanged) ----------------
__global__ __launch_bounds__(64) void gate_k(const float* __restrict__ h2,
                                             const float* __restrict__ gw,
                                             const float* __restrict__ gb,
                                             int* __restrict__ top2i,
                                             float* __restrict__ top2w,
                                             int* __restrict__ counts) {
    int n = blockIdx.x;
    int lane = threadIdx.x;
    float acc[8] = {};
    for (int d = lane; d < DM; d += 64) {
        float hv = h2[(size_t)n * DM + d];
        const float4 g0 = ((const float4*)&gw[d * 8])[0];
        const float4 g1 = ((const float4*)&gw[d * 8])[1];
        acc[0] = fmaf(hv, g0.x, acc[0]); acc[1] = fmaf(hv, g0.y, acc[1]);
        acc[2] = fmaf(hv, g0.z, acc[2]); acc[3] = fmaf(hv, g0.w, acc[3]);
        acc[4] = fmaf(hv, g1.x, acc[4]); acc[5] = fmaf(hv, g1.y, acc[5]);
        acc[6] = fmaf(hv, g1.z, acc[6]); acc[7] = fmaf(hv, g1.w, acc[7]);
    }
#pragma unroll
    for (int e = 0; e < 8; ++e)
        for (int off = 32; off; off >>= 1) acc[e] += __shfl_down(acc[e], off);
    if (lane == 0) {
        float s[8];
#pragma unroll
        for (int e = 0; e < 8; ++e) s[e] = 1.0f / (1.0f + expf(-acc[e])) + gb[e];
        int i0 = 0;
#pragma unroll
        for (int e = 1; e < 8; ++e) if (s[e] > s[i0]) i0 = e;
        int i1 = (i0 == 0) ? 1 : 0;
#pragma unroll
        for (int e = 0; e < 8; ++e) if (e != i0 && s[e] > s[i1]) i1 = e;
        float w0 = s[i0], w1 = s[i1];
        float norm = 1.0f / (w0 + w1 + 1e-20f);
        top2i[n * 2] = i0; top2i[n * 2 + 1] = i1;
        top2w[n * 2] = w0 * norm; top2w[n * 2 + 1] = w1 * norm;
        atomicAdd(&counts[i0], 1);
        atomicAdd(&counts[i1], 1);
    }
}

__global__ void zero16_k(int* p) { if (threadIdx.x < 16) p[threadIdx.x] = 0; }

__global__ void scan_k(const int* __restrict__ counts, int* __restrict__ segs) {
    if (threadIdx.x == 0) {
        segs[0] = 0;
        for (int e = 0; e < NE; ++e) segs[e + 1] = segs[e] + counts[e];
    }
}

__global__ void scatter_k(const int* __restrict__ top2i, const float* __restrict__ top2w,
                          const int* __restrict__ segs, int* __restrict__ cursor,
                          int* __restrict__ list, float* __restrict__ wslot,
                          int* __restrict__ slot_of) {
    int idx = blockIdx.x * blockDim.x + threadIdx.x;
    if (idx >= NTOK * 2) return;
    int e = top2i[idx];
    int pos = segs[e] + atomicAdd(&cursor[e], 1);
    list[pos] = idx >> 1;
    wslot[pos] = top2w[idx];
    slot_of[idx] = pos;
}

// ---------------- bf16 MFMA GEMM (MoE path) ----------------
template <int EPI, int MOE, int GATHER>
__global__ __launch_bounds__(256) void mgemm_k(const u16* __restrict__ A,
                                               const u16* __restrict__ Bt,
                                               const float* __restrict__ R,
                                               const float* __restrict__ wslot,
                                               const int* __restrict__ list,
                                               const int* __restrict__ segs,
                                               float* __restrict__ Cf,
                                               u16* __restrict__ Cb,
                                               int M, int N, int K) {
    __shared__ u16 As[128 * 40];
    __shared__ u16 Bs[128 * 40];
    int e = MOE ? blockIdx.z : 0;
    int base = 0, cnt = M;
    if (MOE) { base = segs[e]; cnt = segs[e + 1] - base; }
    int m0 = blockIdx.y * 128;
    if (m0 >= cnt) return;
    int n0 = blockIdx.x * 128;
    const u16* Bte = Bt + (size_t)e * N * K;
    int t = threadIdx.x;
    int l = t & 63, w = t >> 6;
    int wr = w >> 1, wc = w & 1;
    int srow = t >> 2, scol = (t & 3) << 3;
    const u16* ag[2];
    const u16* bg[2];
#pragma unroll
    for (int i = 0; i < 2; ++i) {
        int r = m0 + i * 64 + srow;
        int ar;
        if (MOE) {
            int rc = r < cnt ? r : cnt - 1;
            ar = GATHER ? list[base + rc] : base + rc;
        } else {
            ar = r;
        }
        ag[i] = A + (size_t)ar * K + scol;
        bg[i] = Bte + (size_t)(n0 + i * 64 + srow) * K + scol;
    }
    f4v acc[4][4];
#pragma unroll
    for (int m = 0; m < 4; ++m)
#pragma unroll
        for (int n = 0; n < 4; ++n) acc[m][n] = (f4v)0.0f;
    int kh = (l >> 4) << 3;
    for (int k0 = 0; k0 < K; k0 += 32) {
        b8v va0 = *(const b8v*)(ag[0] + k0);
        b8v va1 = *(const b8v*)(ag[1] + k0);
        b8v vb0 = *(const b8v*)(bg[0] + k0);
        b8v vb1 = *(const b8v*)(bg[1] + k0);
        __syncthreads();
        *(b8v*)&As[srow * 40 + scol] = va0;
        *(b8v*)&As[(64 + srow) * 40 + scol] = va1;
        *(b8v*)&Bs[srow * 40 + scol] = vb0;
        *(b8v*)&Bs[(64 + srow) * 40 + scol] = vb1;
        __syncthreads();
        b8v af[4], bf[4];
#pragma unroll
        for (int m = 0; m < 4; ++m)
            af[m] = *(const b8v*)&As[(wr * 64 + m * 16 + (l & 15)) * 40 + kh];
#pragma unroll
        for (int n = 0; n < 4; ++n)
            bf[n] = *(const b8v*)&Bs[(wc * 64 + n * 16 + (l & 15)) * 40 + kh];
#pragma unroll
        for (int m = 0; m < 4; ++m)
#pragma unroll
            for (int n = 0; n < 4; ++n)
                acc[m][n] = __builtin_amdgcn_mfma_f32_16x16x32_bf16(af[m], bf[n], acc[m][n], 0, 0, 0);
    }
#pragma unroll
    for (int m = 0; m < 4; ++m) {
        int r0l = m0 + wr * 64 + m * 16 + ((l >> 4) << 2);
#pragma unroll
        for (int n = 0; n < 4; ++n) {
            int col = n0 + wc * 64 + n * 16 + (l & 15);
            f4v c = acc[m][n];
#pragma unroll
            for (int j = 0; j < 4; ++j) {
                int row = r0l + j;
                if (MOE && row >= cnt) continue;
                float v = c[j];
                if (EPI == 1) {
                    v = silu_f(v);
                    Cb[(size_t)(base + row) * N + col] = f2b(v);
                } else if (EPI == 2) {
                    size_t idx = (size_t)row * N + col;
                    Cf[idx] = v + R[idx];
                } else if (EPI == 3) {
                    Cf[(size_t)(base + row) * N + col] = v * wslot[base + row];
                } else {
                    Cf[(size_t)row * N + col] = v;
                }
            }
        }
    }
}

// ---------------- combine ----------------
__global__ __launch_bounds__(256) void combine_k(const float* __restrict__ eout,
                                                 const int* __restrict__ slot_of,
                                                 float* __restrict__ out) {
    int idx = blockIdx.x * blockDim.x + threadIdx.x;
    int n = idx >> 8;
    int c = idx & 255;
    const float4 a = ((const float4*)(eout + (size_t)slot_of[n * 2] * DM))[c];
    const float4 b = ((const float4*)(eout + (size_t)slot_of[n * 2 + 1] * DM))[c];
    float4 o = ((float4*)out)[idx];
    o.x += a.x + b.x; o.y += a.y + b.y; o.z += a.z + b.z; o.w += a.w + b.w;
    ((float4*)out)[idx] = o;
}

extern "C" void kernel_launch(void* const* d_in, const int* in_sizes, int n_in,
                              void* d_out, int out_size, void* d_ws, size_t ws_size,
                              hipStream_t stream) {
    (void)in_sizes; (void)n_in; (void)out_size; (void)ws_size;
    const float* x   = (const float*)d_in[0];
    const float* anw = (const float*)d_in[1];
    const float* wq  = (const float*)d_in[2];
    const float* wk  = (const float*)d_in[3];
    const float* wv  = (const float*)d_in[4];
    const float* wo  = (const float*)d_in[5];
    const float* fnw = (const float*)d_in[6];
    const float* gw  = (const float*)d_in[7];
    const float* gb  = (const float*)d_in[8];
    const float* ew1 = (const float*)d_in[9];
    const float* ew2 = (const float*)d_in[10];
    const float* sw1 = (const float*)d_in[11];
    const float* sw2 = (const float*)d_in[12];
    float* out = (float*)d_out;

#define WSOFF(mb) ((char*)d_ws + (size_t)(mb) * 1048576)
    // weights (persistent): 0..82 MB
    u16* qkvT_h = (u16*)WSOFF(0);    // 1536x1024
    u16* qkvT_l = (u16*)WSOFF(3);
    u16* woT_h  = (u16*)WSOFF(6);    // 1024x1024
    u16* woT_l  = (u16*)WSOFF(8);
    u16* sw1t   = (u16*)WSOFF(10);   // 2048x1024
    u16* sw2t   = (u16*)WSOFF(14);   // 1024x2048
    u16* ew1t   = (u16*)WSOFF(18);   // 8 x 2048x1024
    u16* ew2t   = (u16*)WSOFF(50);   // 8 x 1024x2048
    // activations (lifetime-overlapped):
    float* qkv  = (float*)WSOFF(82);   // 4096x1536 f32 (82..106); dead after vtrans
    float* ao   = (float*)WSOFF(82);   // attn_out f32 (82..98)
    float* h2f  = (float*)WSOFF(82);   // h2 f32 (82..98)
    u16* h_hi   = (u16*)WSOFF(106);    // h split (106..122)
    u16* h_lo   = (u16*)WSOFF(114);
    u16* ao_hi  = (u16*)WSOFF(106);    // ao split (106..122)
    u16* ao_lo  = (u16*)WSOFF(114);
    u16* q_hi   = (u16*)WSOFF(122);    // q split (122..138)
    u16* q_lo   = (u16*)WSOFF(130);
    u16* k_hi   = (u16*)WSOFF(138);    // k split (138..142)
    u16* k_lo   = (u16*)WSOFF(140);
    u16* vT_hi  = (u16*)WSOFF(142);    // vT split (142..146)
    u16* vT_lo  = (u16*)WSOFF(144);
    float* x1   = (float*)WSOFF(146);  // x1 f32 (146..162)
    u16* h2b    = (u16*)WSOFF(162);    // h2 bf16 (162..170)
    u16* midb   = (u16*)WSOFF(170);    // shared mid bf16 (170..186)
    u16* hmidb  = (u16*)WSOFF(122);    // routed mid bf16 (122..154); after attn/Wo dead
    float* eoutb = (float*)WSOFF(154); // expert out f32 (154..186)
    int* meta0  = (int*)WSOFF(186);
    int*   top2i  = meta0;
    float* top2w  = (float*)(meta0 + 8192);
    int*   counts = meta0 + 16384;
    int*   cursor = meta0 + 16392;
    int*   segs   = meta0 + 16400;
    int*   list   = meta0 + 16416;
    float* wslot  = (float*)(meta0 + 16416 + 8192);
    int*   slot_of = meta0 + 16416 + 16384;

    // ---- weight prep ----
    tcast2_k<<<dim3(32, 32), 256, 0, stream>>>(wq, qkvT_h, qkvT_l, DM, 1024);
    tcast2_k<<<dim3(8, 32), 256, 0, stream>>>(wk, qkvT_h + 1024 * 1024, qkvT_l + 1024 * 1024, DM, 256);
    tcast2_k<<<dim3(8, 32), 256, 0, stream>>>(wv, qkvT_h + 1280 * 1024, qkvT_l + 1280 * 1024, DM, 256);
    tcast2_k<<<dim3(32, 32), 256, 0, stream>>>(wo, woT_h, woT_l, DM, DM);
    tcast_k<<<dim3(NFF / 32, DM / 32, 1), 256, 0, stream>>>(sw1, sw1t, DM, NFF);
    tcast_k<<<dim3(DM / 32, NFF / 32, 1), 256, 0, stream>>>(sw2, sw2t, NFF, DM);
    tcast_k<<<dim3(NFF / 32, DM / 32, NE), 256, 0, stream>>>(ew1, ew1t, DM, NFF);
    tcast_k<<<dim3(DM / 32, NFF / 32, NE), 256, 0, stream>>>(ew2, ew2t, NFF, DM);

    // 1. h = rmsnorm(x) -> hi/lo split
    rmsnorm2_k<0><<<NTOK, 256, 0, stream>>>(x, anw, h_hi, h_lo, nullptr);
    // 2. fused QKV projection (split MFMA) -> qkv f32
    sgemm_k<0><<<dim3(QKVN / 128, NTOK / 128), 256, 0, stream>>>(
        h_hi, h_lo, qkvT_h, qkvT_l, nullptr, qkv, NTOK, QKVN, DM);
    // 3. RoPE on q and k parts
    rope2_k<<<(NTOK * NH * 32 + 255) / 256, 256, 0, stream>>>(qkv, NH, 0);
    rope2_k<<<(NTOK * NKV * 32 + 255) / 256, 256, 0, stream>>>(qkv, NKV, 1024);
    // 3.5 split casts for attention
    scast_k<<<2048, 256, 0, stream>>>(qkv, QKVN, 0, 1024, q_hi, q_lo);
    scast_k<<<512, 256, 0, stream>>>(qkv, QKVN, 1024, 256, k_hi, k_lo);
    vtrans_k<<<dim3(8, 128), 256, 0, stream>>>(qkv, vT_hi, vT_lo);
    // 4. attention -> ao (f32)
    mattn_k<<<dim3(TSEQ / 128, 32), 256, 0, stream>>>(q_hi, q_lo, k_hi, k_lo, vT_hi, vT_lo, ao);
    // 5. x1 = ao @ wo + x
    scast_k<<<2048, 256, 0, stream>>>(ao, DM, 0, DM, ao_hi, ao_lo);
    sgemm_k<2><<<dim3(DM / 128, NTOK / 128), 256, 0, stream>>>(
        ao_hi, ao_lo, woT_h, woT_l, x, x1, NTOK, DM, DM);
    // 6. h2 = rmsnorm(x1) -> f32 (gate) + bf16 (MoE)
    rmsnorm2_k<1><<<NTOK, 256, 0, stream>>>(x1, fnw, h2b, nullptr, h2f);
    // 7. gate + routing
    zero16_k<<<1, 64, 0, stream>>>(counts);
    gate_k<<<NTOK, 64, 0, stream>>>(h2f, gw, gb, top2i, top2w, counts);
    scan_k<<<1, 1, 0, stream>>>(counts, segs);
    scatter_k<<<32, 256, 0, stream>>>(top2i, top2w, segs, cursor, list, wslot, slot_of);
    // 8. shared expert
    mgemm_k<1, 0, 0><<<dim3(NFF / 128, NTOK / 128, 1), 256, 0, stream>>>(
        h2b, sw1t, nullptr, nullptr, nullptr, nullptr, nullptr, midb, NTOK, NFF, DM);
    mgemm_k<2, 0, 0><<<dim3(DM / 128, NTOK / 128, 1), 256, 0, stream>>>(
        midb, sw2t, x1, nullptr, nullptr, nullptr, out, nullptr, NTOK, DM, NFF);
    // 9. routed experts
    mgemm_k<1, 1, 1><<<dim3(NFF / 128, NTOK / 128, NE), 256, 0, stream>>>(
        h2b, ew1t, nullptr, nullptr, list, segs, nullptr, hmidb, NTOK, NFF, DM);
    mgemm_k<3, 1, 0><<<dim3(DM / 128, NTOK / 128, NE), 256, 0, stream>>>(
        hmidb, ew2t, nullptr, wslot, nullptr, segs, eoutb, nullptr, 2 * NTOK, DM, NFF);
    combine_k<<<NTOK, 256, 0, stream>>>(eoutb, slot_of, out);
#undef WSOFF
}